// Round 6
// baseline (172.136 us; speedup 1.0000x reference)
//
#include <hip/hip_runtime.h>
#include <hip/hip_bf16.h>
#include <stdint.h>

#define NF 51
#define NF2 (51*51)
#define WIN 100
#define EMB 12
#define FIN 112
#define HID 60
#define NPRUNE 1561
#define SORTN 4096

// ws layout (prepped by prune_kernel; forward stages first WS_STAGE bytes linearly)
#define WS_WX    0        // f16 [112][104] Wx rows   (k<100 real; 100..103 = 0)
#define WS_W1    23296    // f16 [64][104]  w1 rows   (k==100 -> b1; pads 0)
#define WS_W2    36608    // f16 [112][72]  w2 rows   (k==60  -> b2; pads 0)
#define WS_ADJ   52736    // f16 [64][72]   adj rows  (k=51..62 -> E2, k=63 -> 1)
#define WS_YTI   61952    // f16 [112][13]  yT D-fold init (gw_emb | gcn_b/one)
#define WS_STAGE 52736

// forward LDS: per group, sHX [102][104] f16 (x-staging ALIASED with h2) + yT.
#define LDS_GRP0 52736
#define YT_OFF   10608    // f16 units into group region (sHX = 102*104 f16)
#define GRP_SPAN 53472    // bytes: sHX 21216 + yT 32256
#define LDS_TOTAL 159680

typedef _Float16 f16;
typedef _Float16 f16x8 __attribute__((ext_vector_type(8)));
typedef _Float16 f16x4 __attribute__((ext_vector_type(4)));
typedef float f32x4 __attribute__((ext_vector_type(4)));

__device__ __forceinline__ float fast_tanh(float x) {
  float xa = fminf(fmaxf(x, -15.f), 15.f);
  float e = __expf(2.f * xa);
  return (e - 1.f) * __builtin_amdgcn_rcpf(e + 1.f);
}

// T4 barrier: LDS-visibility wait only; vmcnt NOT drained.
#define BAR() do { asm volatile("s_waitcnt lgkmcnt(0)" ::: "memory"); \
  __builtin_amdgcn_s_barrier(); asm volatile("" ::: "memory"); } while (0)

// ---------------- Kernel 1: graph construction + greedy prune + prep ----------------
__global__ __launch_bounds__(512) void prune_kernel(const float* __restrict__ embed,
                                                    const float* __restrict__ gcn_w,
                                                    const float* __restrict__ gcn_b,
                                                    const float* __restrict__ w1,
                                                    const float* __restrict__ b1,
                                                    const float* __restrict__ w2,
                                                    const float* __restrict__ b2,
                                                    void* __restrict__ ws) {
  const int t = threadIdx.x;
  char* wsb = (char*)ws;

  if (blockIdx.x == 1) {
    f16* wxT = (f16*)(wsb + WS_WX);
    for (int u = t; u < 112*104; u += 512) {
      int nn = u / 104, k = u - nn*104;
      wxT[u] = (f16)((nn < WIN && k < WIN) ? gcn_w[nn*FIN + k] : 0.f);
    }
    f16* w1T = (f16*)(wsb + WS_W1);
    for (int u = t; u < 64*104; u += 512) {
      int nn = u / 104, k = u - nn*104;
      float v = 0.f;
      if (nn < HID) { if (k < WIN) v = w1[nn*WIN + k]; else if (k == WIN) v = b1[nn]; }
      w1T[u] = (f16)v;
    }
    f16* w2T = (f16*)(wsb + WS_W2);
    for (int u = t; u < 112*72; u += 512) {
      int nn = u / 72, k = u - nn*72;
      float v = 0.f;
      if (nn < WIN) { if (k < HID) v = w2[nn*HID + k]; else if (k == HID) v = b2[nn]; }
      w2T[u] = (f16)v;
    }
    f16* ytI = (f16*)(wsb + WS_YTI);
    for (int u = t; u < 112*13; u += 512) {
      int win = u / 13, e = u - win*13;
      float v = 0.f;
      if (win < WIN) v = (e < 12) ? gcn_w[win*FIN + WIN + e] : gcn_b[win];
      else if (win == WIN && e == 12) v = 1.f;
      ytI[u] = (f16)v;
    }
    return;
  }

  __shared__ float sA[NF * 52];
  __shared__ unsigned long long sKey[SORTN];
  __shared__ float sNrm[NF];
  __shared__ float sDinv[NF];
  __shared__ float sRow[NF];
  __shared__ float sCol[NF];
  __shared__ float sRowS[NF];
  __shared__ float sColS[NF];
  __shared__ float sEmb[NF * EMB];
  __shared__ float sE2[NF * EMB];
  __shared__ unsigned char sMask[NF2];
  __shared__ unsigned long long sSusp[64];
  __shared__ int sCand[256];
  __shared__ int sCnt[17];
  __shared__ int sNS;
  __shared__ int sNC;
  __shared__ int sTotal;

  for (int u = t; u < NF * EMB; u += 512) sEmb[u] = embed[u];
  for (int u = t; u < NF2; u += 512) sMask[u] = 0;
  if (t == 0) { sNS = 0; sNC = 0; sTotal = 0; }
  __syncthreads();
  if (t < NF) {
    float s = 0.f;
    for (int e = 0; e < EMB; e++) { float w = sEmb[t*EMB + e]; s += w * w; }
    sNrm[t] = sqrtf(s);
  }
  __syncthreads();
  for (int u = t; u < NF2; u += 512) {
    int r = u / NF, c = u % NF;
    float d = 0.f;
    for (int e = 0; e < EMB; e++) d += sEmb[r*EMB + e] * sEmb[c*EMB + e];
    sA[r*52 + c] = d / (sNrm[r] * sNrm[c]);
  }
  __syncthreads();

  if (t < NF) {
    float rs = 0.f, cs = 0.f;
    for (int j = 0; j < NF; j++) { rs += sA[t*52 + j]; cs += sA[j*52 + t]; }
    sRow[t] = rs; sCol[t] = cs;
  }
  __syncthreads();

  // ---- STAGE A (cheap): a rejection of (r,c,v) at visit time requires
  // sum_at_visit <= v on BOTH row and col; sums only increase, so
  // sRow0>v || sCol0>v => unconditionally accepted. Survivors = candidates.
  {
    int myCnt = 0;
    for (int u = t; u < NF2; u += 512) {
      int r = u / NF, c = u % NF;
      float v = sA[r*52 + c];
      if (v < 0.f) {
        myCnt++;
        if (sRow[r] <= v && sCol[c] <= v) {
          int slot = atomicAdd(&sNC, 1);
          if (slot < 256) sCand[slot] = u;
        }
      }
    }
    if (myCnt) atomicAdd(&sTotal, myCnt);
  }
  __syncthreads();
  // ---- STAGE B (sharpened): visit-time sum >= S0 + sum(-v_j) over earlier
  // (ascending (v,idx)) negatives in the row/col — every processed entry
  // contributes >= -v_j (accept: -v_j; reject: mx-v_j > -v_j). Candidates
  // passing this bound are definitely accepted; the rest are suspects.
  if (sNC <= 256) {
    const int nC = sNC;
    for (int i = t; i < nC; i += 512) {
      int u = sCand[i];
      int r = u / NF, c = u - r*NF;
      float v = sA[r*52 + c];
      float Pr = 0.f, Pc = 0.f;
      for (int j = 0; j < NF; j++) {
        float a = sA[r*52 + j];
        if (a < 0.f && (a < v || (a == v && r*NF + j < u))) Pr -= a;
        float b = sA[j*52 + c];
        if (b < 0.f && (b < v || (b == v && j*NF + c < u))) Pc -= b;
      }
      bool okS = ((sRow[r] + Pr - v) > 0.f) || ((sCol[c] + Pc - v) > 0.f);
      if (!okS) {
        int slot = atomicAdd(&sNS, 1);
        if (slot < 64) {
          unsigned int b = __float_as_uint(v);   // negative -> monotone map ~b
          sSusp[slot] = ((unsigned long long)(~b) << 32) | (unsigned int)u;
          sMask[u] = 1;
        }
      }
    }
  }
  __syncthreads();
  const bool fastPath = (sTotal > 0) && (sTotal <= NPRUNE) && (sNC <= 256) && (sNS <= 64);

  if (fastPath) {
    if (t < 64) {
      const int lane = t;
      float mx = -3.0e38f;
      for (int u = lane; u < NF2; u += 64) mx = fmaxf(mx, sA[(u / NF)*52 + (u % NF)]);
      for (int o = 32; o > 0; o >>= 1) mx = fmaxf(mx, __shfl_xor(mx, o, 64));
      if (lane < NF) { sRowS[lane] = 0.f; sColS[lane] = 0.f; }
      const int nS = sNS;
      unsigned long long key = (lane < nS) ? sSusp[lane] : ~0ull;
      // in-wave bitonic sort (64 lanes) ascending (value, idx)
      for (int k = 2; k <= 64; k <<= 1) {
        for (int j = k >> 1; j > 0; j >>= 1) {
          unsigned long long other = __shfl_xor(key, j, 64);
          bool up = ((lane & k) == 0);
          bool takeMin = (((lane & j) == 0) == up);
          unsigned long long mn = key < other ? key : other;
          unsigned long long mxk = key < other ? other : key;
          key = takeMin ? mn : mxk;
        }
      }
      // serial exact walk over suspects: visit sums = S0 + exact non-suspect
      // prefix (all accepted) + tracked suspect contributions.
      for (int kk = 0; kk < nS; kk++) {
        unsigned long long kv = __shfl(key, kk, 64);
        unsigned int mb = (unsigned int)(kv >> 32);
        unsigned int idx = (unsigned int)kv;
        float v = __uint_as_float(~mb);            // suspects are negative
        int r = (int)(idx / NF), c = (int)(idx % NF);
        float pr = 0.f, pc = 0.f;
        if (lane < NF) {
          float a = sA[r*52 + lane];
          if (a < 0.f && !sMask[r*NF + lane] &&
              (a < v || (a == v && (unsigned)(r*NF + lane) < idx))) pr = -a;
          float b = sA[lane*52 + c];
          if (b < 0.f && !sMask[lane*NF + c] &&
              (b < v || (b == v && (unsigned)(lane*NF + c) < idx))) pc = -b;
        }
        for (int o = 32; o > 0; o >>= 1) {
          pr += __shfl_xor(pr, o, 64);
          pc += __shfl_xor(pc, o, 64);
        }
        float sumR = sRow[r] + pr + sRowS[r];
        float sumC = sCol[c] + pc + sColS[c];
        bool ok = ((sumR - v) > 0.f) || ((sumC - v) > 0.f);
        if (lane == 0) {
          if (ok) { sA[r*52 + c] = 0.f; sRowS[r] += -v;     sColS[c] += -v; }
          else    { sA[r*52 + c] = mx;  sRowS[r] += mx - v; sColS[c] += mx - v; }
        }
      }
    }
    __syncthreads();
    // all non-suspect negatives accepted -> zero; rejected suspects hold mx>0.
    for (int u = t; u < NF2; u += 512) {
      int r = u / NF, c = u % NF;
      if (sA[r*52 + c] < 0.f) sA[r*52 + c] = 0.f;
    }
  } else {
    // ---- SLOW PATH (exact; compaction + bitonic sort + ballot walk) ----
    int myCnt = 0;
    for (int u = t; u < NF2; u += 512)
      myCnt += (sA[(u / NF)*52 + (u % NF)] < 0.f) ? 1 : 0;
    int incl = myCnt;
    for (int o = 1; o < 64; o <<= 1) {
      int nb = __shfl_up(incl, o, 64);
      if ((t & 63) >= o) incl += nb;
    }
    if ((t & 63) == 63) sCnt[t >> 6] = incl;
    __syncthreads();
    if (t == 0) {
      int run = 0;
      for (int j = 0; j < 8; j++) { int v = sCnt[j]; sCnt[8 + j] = run; run += v; }
      sCnt[16] = run;
    }
    __syncthreads();
    const int total = sCnt[16];
    const int n = (total <= 2048) ? 2048 : SORTN;
    {
      int cpos = sCnt[8 + (t >> 6)] + (incl - myCnt);
      for (int u = t; u < NF2; u += 512) {
        float v = sA[(u / NF)*52 + (u % NF)];
        if (v < 0.f) {
          unsigned int b = __float_as_uint(v);
          sKey[cpos++] = ((unsigned long long)(~b) << 32) | (unsigned int)u;
        }
      }
      for (int u = total + t; u < n; u += 512) sKey[u] = ~0ull;
    }
    __syncthreads();
    for (int kk = 2; kk <= n; kk <<= 1) {
      for (int jj = kk >> 1; jj > 0; jj >>= 1) {
        for (int u = t; u < n; u += 512) {
          int l = u ^ jj;
          if (l > u) {
            unsigned long long a = sKey[u], b = sKey[l];
            bool up = ((u & kk) == 0);
            if ((a > b) == up) { sKey[u] = b; sKey[l] = a; }
          }
        }
        __syncthreads();
      }
    }

    if (t < 64) {
      const int lane = t;
      float mx = -3.0e38f;
      for (int u = lane; u < NF2; u += 64) mx = fmaxf(mx, sA[(u / NF)*52 + (u % NF)]);
      for (int o = 32; o > 0; o >>= 1) mx = fmaxf(mx, __shfl_xor(mx, o, 64));

      int pruned = 0, pos = 0;
      bool toP2 = false;
      while (pruned < NPRUNE && !toP2) {
        int myi = pos + lane;
        unsigned long long kv = (myi < n) ? sKey[myi] : ~0ull;
        unsigned int mb  = (unsigned int)(kv >> 32);
        unsigned int idx = (unsigned int)kv;
        unsigned int vb  = (mb & 0x80000000u) ? (mb & 0x7FFFFFFFu) : ~mb;
        float v = __uint_as_float(vb);
        bool elig = (v < 0.f) && (idx < (unsigned)NF2);
        int r = 0, c2 = 0; bool okl = false;
        if (elig) {
          r = (int)(idx / NF); c2 = (int)(idx % NF);
          float sr = sRow[r], sc = sCol[c2];
          okl = ((sr - v) > 0.f) || ((sc - v) > 0.f);
        }
        unsigned long long bal = __ballot(okl);
        unsigned long long nb = ~bal;
        int nok = (nb == 0ull) ? 64 : (int)__builtin_ctzll(nb);
        int rem = NPRUNE - pruned;
        int take = nok < rem ? nok : rem;
        if (lane < take) {
          sA[r*52 + c2] = 0.f;
          atomicAdd(&sRow[r], -v);
          atomicAdd(&sCol[c2], -v);
        }
        pruned += take; pos += take;
        if (pruned >= NPRUNE) break;
        if (take == 64) continue;
        unsigned int bvb = (unsigned int)__builtin_amdgcn_readlane((int)vb, take);
        int bidx = __builtin_amdgcn_readlane((int)idx, take);
        float bv = __uint_as_float(bvb);
        if (!(bv < 0.f) || bidx >= NF2) { toP2 = true; break; }
        int br = bidx / NF, bc = bidx % NF;
        float sr = sRow[br], sc = sCol[bc];
        bool ok = ((sr - bv) > 0.f) || ((sc - bv) > 0.f);
        if (ok) {
          if (lane == 0) {
            sA[br*52 + bc] = 0.f;
            sRow[br] = sr - bv; sCol[bc] = sc - bv;
          }
          pruned++; pos++;
        } else {
          if (lane == 0) {
            sA[br*52 + bc] = mx;
            sRow[br] = sr + (mx - bv); sCol[bc] = sc + (mx - bv);
          }
          pos++;
        }
      }
      if (toP2) {
        for (int guard = 0; guard < 40000 && pruned < NPRUNE; guard++) {
          float bv = 3.0e38f; int bidx = NF2;
          for (int u = lane; u < NF2; u += 64) {
            float v = sA[(u / NF)*52 + (u % NF)];
            if (v < bv) { bv = v; bidx = u; }
          }
          for (int o = 32; o > 0; o >>= 1) {
            float ov = __shfl_xor(bv, o, 64);
            int  oi = __shfl_xor(bidx, o, 64);
            if (ov < bv || (ov == bv && oi < bidx)) { bv = ov; bidx = oi; }
          }
          int br = bidx / NF, bc = bidx % NF;
          float sr = sRow[br], sc = sCol[bc];
          bool ok = ((sr - bv) > 0.f) || ((sc - bv) > 0.f);
          if (ok) {
            if (bv == 0.f) break;
            if (lane == 0) { sA[br*52+bc] = 0.f; sRow[br] = sr - bv; sCol[bc] = sc - bv; }
            pruned++;
          } else {
            if (bv == mx) break;
            if (lane == 0) { sA[br*52+bc] = mx; sRow[br] = sr + (mx-bv); sCol[bc] = sc + (mx-bv); }
          }
        }
      }
    }
  }
  __syncthreads();

  if (t < NF) {
    float deg = 0.f;
    for (int j = 0; j < NF; j++) {
      float a = sA[t*52 + j];
      float bin = (a != 0.f) ? 1.f : 0.f;
      if (j == t) bin += 1.f;
      deg += bin;
    }
    sDinv[t] = 1.f / sqrtf(deg);
  }
  __syncthreads();

  float* sN = (float*)sKey;   // sKey dead; reuse as norm_adj [51][52]
  for (int u = t; u < NF * 52; u += 512) {
    int r = u / 52, c = u % 52;
    float v = 0.f;
    if (c < NF) {
      float a = sA[r*52 + c];
      float bin = (a != 0.f) ? 1.f : 0.f;
      if (r == c) bin += 1.f;
      v = sDinv[r] * bin * sDinv[c];
    }
    sN[u] = v;
  }
  __syncthreads();

  // E2 = norm_adj @ embed  [51][12]
  for (int u = t; u < NF * EMB; u += 512) {
    int i = u / EMB, e = u % EMB;
    float s2 = 0.f;
    for (int j = 0; j < NF; j++) s2 += sN[i*52 + j] * sEmb[j*EMB + e];
    sE2[u] = s2;
  }
  __syncthreads();

  // adjT with rank-13 D-fold in k=51..63: cols 51..62 <- E2, col 63 <- 1
  f16* adjT = (f16*)(wsb + WS_ADJ);
  for (int u = t; u < 64*72; u += 512) {
    int r = u / 72, k = u - r*72;
    float v = 0.f;
    if (r < NF) {
      if (k < NF) v = sN[r*52 + k];
      else if (k < 63) v = sE2[r*EMB + (k - 51)];
      else if (k == 63) v = 1.f;
    }
    adjT[u] = (f16)v;
  }
}

// ---------------- Kernel 2: persistent fused MFMA forward ----------------
// 256 blocks x 1024 thr = 16 waves/CU; two 8-wave pair-groups share weights.
// TWO barriers per pair: x-staging is PER-WAVE (each wave loads/writes exactly
// the 16 sHX rows its own S1 reads; global address is perfectly linear =>
// coalesced) so STVX->S1 is wave-local (lgkmcnt only). STVX masked to
// own-SAMPLE rows; boundary lanes read stale bytes that feed only
// masked-at-write MFMA outputs (verified via D-layout for S1/S3/S4).
// K-folds: D/gcn_b ride yT cols 51..63; b1 rides w1T k=100; b2 rides w2T k=60.
__global__ __launch_bounds__(1024, 4) void forward_kernel(
    const float* __restrict__ x, const void* __restrict__ ws,
    float* __restrict__ out, int nPairs, int nIt, int ppb) {
  __shared__ __align__(16) char smem[LDS_TOTAL];
  f16* wxT = (f16*)(smem + WS_WX);
  f16* w1T = (f16*)(smem + WS_W1);
  f16* w2T = (f16*)(smem + WS_W2);

  const int t = threadIdx.x;
  const int wv = t >> 6, lane = t & 63;
  const int gq = wv >> 3, wq = wv & 7;
  const int c = lane & 15, g = lane >> 4;
  const int s = wq >> 2, mt = wq & 3;
  const int rowA = 51*s + 16*mt + c;
  f16* sHX = (f16*)(smem + LDS_GRP0 + gq*GRP_SPAN);  // [102][104]: x then h2
  f16* yT = sHX + YT_OFF;                            // [2][112][72]

  // one-time: stage weights (52736 B linear), zero activation regions
  {
    const f32x4* w4 = (const f32x4*)ws;
    f32x4* s4 = (f32x4*)smem;
    #pragma unroll
    for (int u = 0; u < 4; u++) { int i = t + u*1024; if (i < 3296) s4[i] = w4[i]; }
    f32x4 z = {0.f,0.f,0.f,0.f};
    f32x4* za = (f32x4*)(smem + LDS_GRP0);
    #pragma unroll
    for (int u = 0; u < 7; u++) { int i = t + u*1024; if (i < 6684) za[i] = z; }
  }
  __syncthreads();
  // D-fold init into yT cols 51..63 (both groups, both samples); persists all
  // pairs (S1 writes only node-cols <= 50).
  {
    const f16* ytI = (const f16*)((const char*)ws + WS_YTI);
    f16* yA = (f16*)(smem + LDS_GRP0) + YT_OFF;
    f16* yB = (f16*)(smem + LDS_GRP0 + GRP_SPAN) + YT_OFF;
    for (int u = t; u < 112*13; u += 1024) {
      int win = u / 13, e = u - win*13;
      f16 v = ytI[u];
      int o = win*72 + 51 + e;
      yA[o] = v; yA[8064 + o] = v; yB[o] = v; yB[8064 + o] = v;
    }
  }
  const f16* adjG = (const f16*)((const char*)ws + WS_ADJ);
  f16x8 adjf[4][2];
  #pragma unroll
  for (int N = 0; N < 4; N++) {
    const f16* bp = &adjG[(16*N + c)*72 + 8*g];
    adjf[N][0] = *(const f16x8*)(bp);
    adjf[N][1] = *(const f16x8*)(bp + 32);
  }
  __syncthreads();

  const int s2a = (wq == 7) ? 1 : 0;
  const int wta = (wq == 7) ? 0 : wq;
  const int wtb = wq + 1;                  // second S2 task (s2=1), wq < 6
  const bool aOk = (16*mt + c) < NF;
  const int pair0 = blockIdx.x * ppb;
  const int rowBase = 51*s + 16*mt;
  // own-sample rows only: mt<3 -> 16 rows (400 float4); mt==3 -> 3 rows (75)
  const int uMax = (mt < 3) ? 400 : 75;

  float4 px0, px1, px2, px3, px4, px5, px6;
  #define LOADP(PI) { \
    const float4* xb = (const float4*)(x + (size_t)(PI)*10200 + (size_t)rowBase*100); \
    px0 = xb[lane]; px1 = xb[lane+64]; \
    if (lane + 128 < uMax) px2 = xb[lane+128]; \
    if (lane + 192 < uMax) px3 = xb[lane+192]; \
    if (lane + 256 < uMax) px4 = xb[lane+256]; \
    if (lane + 320 < uMax) px5 = xb[lane+320]; \
    if (lane + 384 < uMax) px6 = xb[lane+384]; \
    if (mt == 3 && lane + 64 >= uMax) px1 = px0; }
  #define STV1(PX, I) { int u = lane + 64*(I); if (u < uMax) { \
    int row = u / 25, q4 = (u - row*25)*4; \
    f16x4 hv = {(f16)(PX).x,(f16)(PX).y,(f16)(PX).z,(f16)(PX).w}; \
    *(f16x4*)&sHX[(rowBase+row)*104 + q4] = hv; } }
  #define STVX() { STV1(px0,0) STV1(px1,1) STV1(px2,2) STV1(px3,3) \
                   STV1(px4,4) STV1(px5,5) STV1(px6,6) }

  { int pi = pair0 + gq; if (pi < nPairs) LOADP(pi); }

  #pragma unroll 1
  for (int p = 0; p < nIt; p++) {
    const int pairIdx = pair0 + 2*p + gq;
    const bool valid = pairIdx < nPairs;
    const bool nvalid = (p + 1 < nIt) && (pairIdx + 2 < nPairs);
    const f16x8 zero8 = {(f16)0,(f16)0,(f16)0,(f16)0,(f16)0,(f16)0,(f16)0,(f16)0};
    const f32x4 zacc = {0.f,0.f,0.f,0.f};

    // ---- per-wave x staging (own rows; compiler waits vmcnt on px use) ----
    if (valid) STVX();
    // issue next pair's loads (latency spans the whole iteration)
    if (nvalid) LOADP(pairIdx + 2);
    asm volatile("s_waitcnt lgkmcnt(0)" ::: "memory");
    __builtin_amdgcn_sched_barrier(0);

    // ---- S1: y = x @ Wx^T ; A-frags = own sX rows; write yT (cols <= 50) ----
    if (valid) {
      const f16* aB = &sHX[rowA*104];
      const f16x8 a0 = *(const f16x8*)(aB +  0 + 8*g);
      const f16x8 a1 = *(const f16x8*)(aB + 32 + 8*g);
      const f16x8 a2 = *(const f16x8*)(aB + 64 + 8*g);
      f16x8 a3 = zero8;
      if (g == 0) a3 = *(const f16x8*)(aB + 96);   // cols 100..103 stale * 0-weights
      f16* yTs = yT + s*8064;
      const int nodeW = 16*mt + 4*g;
      #pragma unroll
      for (int N = 0; N < 7; N++) {
        const f16* bp = &wxT[(16*N + c)*104 + 8*g];
        f16x8 b3v = zero8;
        if (g == 0) b3v = *(const f16x8*)(bp + 96);
        f32x4 acc = zacc;
        acc = __builtin_amdgcn_mfma_f32_16x16x32_f16(a0, *(const f16x8*)(bp     ), acc, 0, 0, 0);
        acc = __builtin_amdgcn_mfma_f32_16x16x32_f16(a1, *(const f16x8*)(bp + 32), acc, 0, 0, 0);
        acc = __builtin_amdgcn_mfma_f32_16x16x32_f16(a2, *(const f16x8*)(bp + 64), acc, 0, 0, 0);
        acc = __builtin_amdgcn_mfma_f32_16x16x32_f16(a3, b3v, acc, 0, 0, 0);
        const int col = 16*N + c;
        if (mt < 3) {
          f16x4 hv = {(f16)acc[0],(f16)acc[1],(f16)acc[2],(f16)acc[3]};
          *(f16x4*)&yTs[col*72 + nodeW] = hv;
        } else {
          #pragma unroll
          for (int r2 = 0; r2 < 4; r2++)
            if (nodeW + r2 < NF) yTs[col*72 + nodeW + r2] = (f16)acc[r2];
        }
      }
    }
    BAR();   // bar B: yT ready; S2(p-1) reads were done via bar C(p-1)

    // ---- S2: h2 = relu(adj_ext @ y_ext) -> sHX (clobbers sX; D-fold rides) ----
    if (valid) {
      {
        const f16* ap = &yT[s2a*8064 + (16*wta + c)*72 + 8*g];
        const f16x8 a0 = *(const f16x8*)(ap);
        const f16x8 a1 = *(const f16x8*)(ap + 32);
        #pragma unroll
        for (int N = 0; N < 4; N++) {
          f32x4 acc = zacc;
          acc = __builtin_amdgcn_mfma_f32_16x16x32_f16(a0, adjf[N][0], acc, 0, 0, 0);
          acc = __builtin_amdgcn_mfma_f32_16x16x32_f16(a1, adjf[N][1], acc, 0, 0, 0);
          const int nd = 16*N + c;
          const int cb = 16*wta + 4*g;
          if (nd < NF && cb < 104) {
            f16x4 hv = {(f16)fmaxf(acc[0],0.f),(f16)fmaxf(acc[1],0.f),
                        (f16)fmaxf(acc[2],0.f),(f16)fmaxf(acc[3],0.f)};
            *(f16x4*)&sHX[(51*s2a + nd)*104 + cb] = hv;
          }
        }
      }
      if (wq < 6) {
        const f16* ap = &yT[8064 + (16*wtb + c)*72 + 8*g];
        const f16x8 a0 = *(const f16x8*)(ap);
        const f16x8 a1 = *(const f16x8*)(ap + 32);
        #pragma unroll
        for (int N = 0; N < 4; N++) {
          f32x4 acc = zacc;
          acc = __builtin_amdgcn_mfma_f32_16x16x32_f16(a0, adjf[N][0], acc, 0, 0, 0);
          acc = __builtin_amdgcn_mfma_f32_16x16x32_f16(a1, adjf[N][1], acc, 0, 0, 0);
          const int nd = 16*N + c;
          const int cb = 16*wtb + 4*g;
          if (nd < NF && cb < 104) {
            f16x4 hv = {(f16)fmaxf(acc[0],0.f),(f16)fmaxf(acc[1],0.f),
                        (f16)fmaxf(acc[2],0.f),(f16)fmaxf(acc[3],0.f)};
            *(f16x4*)&sHX[(51 + nd)*104 + cb] = hv;
          }
        }
      }
    }
    BAR();   // bar C: h2 ready; yT reads done

    // ---- S3 (h3 in registers) -> lane-exchange -> S4 -> global ----
    if (valid) {
      const f16* bB = &sHX[rowA*104 + 8*g];   // boundary/overread rows: masked
      const f16x8 hb0 = *(const f16x8*)(bB);
      const f16x8 hb1 = *(const f16x8*)(bB + 32);
      const f16x8 hb2 = *(const f16x8*)(bB + 64);
      f16x8 hb3 = zero8;
      if (g == 0) hb3 = *(const f16x8*)(bB + 96);   // col100==1 -> b1 via w1T k=100

      f32x4 ac0, ac1, ac2, ac3;
      #define S3N(NN, ACC) { \
        const f16* ap = &w1T[(16*(NN) + c)*104 + 8*g]; \
        f16x8 a3v = zero8; if (g == 0) a3v = *(const f16x8*)(ap + 96); \
        ACC = zacc; \
        ACC = __builtin_amdgcn_mfma_f32_16x16x32_f16(*(const f16x8*)(ap     ), hb0, ACC, 0, 0, 0); \
        ACC = __builtin_amdgcn_mfma_f32_16x16x32_f16(*(const f16x8*)(ap + 32), hb1, ACC, 0, 0, 0); \
        ACC = __builtin_amdgcn_mfma_f32_16x16x32_f16(*(const f16x8*)(ap + 64), hb2, ACC, 0, 0, 0); \
        ACC = __builtin_amdgcn_mfma_f32_16x16x32_f16(a3v, hb3, ACC, 0, 0, 0); }
      S3N(0, ac0) S3N(1, ac1) S3N(2, ac2) S3N(3, ac3)
      #undef S3N

      union Qu { f16x4 h; int2 i; };
      Qu q0, q1, q2, q3;
      { f16x4 v = {(f16)fast_tanh(ac0[0]),(f16)fast_tanh(ac0[1]),(f16)fast_tanh(ac0[2]),(f16)fast_tanh(ac0[3])}; q0.h = v; }
      { f16x4 v = {(f16)fast_tanh(ac1[0]),(f16)fast_tanh(ac1[1]),(f16)fast_tanh(ac1[2]),(f16)fast_tanh(ac1[3])}; q1.h = v; }
      { f16x4 v = {(f16)fast_tanh(ac2[0]),(f16)fast_tanh(ac2[1]),(f16)fast_tanh(ac2[2]),(f16)fast_tanh(ac2[3])}; q2.h = v; }
      { f16x4 v = {(f16)fast_tanh(ac3[0]),(f16)fast_tanh(ac3[1]),(f16)fast_tanh(ac3[2]),(f16)fast_tanh(ac3[3])}; q3.h = v; }
      // h3 cols 60..63 = {1,0,0,0}: k=60 one feeds b2 via w2T col 60
      if (g == 3) { q3.i.x = 0x00003C00; q3.i.y = 0; }

      const int srcA = c + 16*((2*g) & 3);
      const int srcB = srcA + 16;
      int A0x=__shfl(q0.i.x,srcA,64), A0y=__shfl(q0.i.y,srcA,64);
      int A1x=__shfl(q1.i.x,srcA,64), A1y=__shfl(q1.i.y,srcA,64);
      int A2x=__shfl(q2.i.x,srcA,64), A2y=__shfl(q2.i.y,srcA,64);
      int A3x=__shfl(q3.i.x,srcA,64), A3y=__shfl(q3.i.y,srcA,64);
      int B0x=__shfl(q0.i.x,srcB,64), B0y=__shfl(q0.i.y,srcB,64);
      int B1x=__shfl(q1.i.x,srcB,64), B1y=__shfl(q1.i.y,srcB,64);
      int B2x=__shfl(q2.i.x,srcB,64), B2y=__shfl(q2.i.y,srcB,64);
      int B3x=__shfl(q3.i.x,srcB,64), B3y=__shfl(q3.i.y,srcB,64);
      const bool hiN = (g & 2) != 0;
      union U8 { int i[4]; f16x8 v; } hA, hB;
      hA.i[0] = hiN ? A1x : A0x; hA.i[1] = hiN ? A1y : A0y;
      hA.i[2] = hiN ? B1x : B0x; hA.i[3] = hiN ? B1y : B0y;
      hB.i[0] = hiN ? A3x : A2x; hB.i[1] = hiN ? A3y : A2y;
      hB.i[2] = hiN ? B3x : B2x; hB.i[3] = hiN ? B3y : B2y;

      float* ob = out + (size_t)pairIdx * 10200 + (size_t)rowA * 100;
      #pragma unroll
      for (int N = 0; N < 7; N++) {
        const f16* ap = &w2T[(16*N + c)*72 + 8*g];
        f32x4 acc = zacc;
        acc = __builtin_amdgcn_mfma_f32_16x16x32_f16(*(const f16x8*)(ap     ), hA.v, acc, 0, 0, 0);
        acc = __builtin_amdgcn_mfma_f32_16x16x32_f16(*(const f16x8*)(ap + 32), hB.v, acc, 0, 0, 0);
        const int colb = 16*N + 4*g;
        if (aOk && colb < WIN) {
          float4 ov = {fast_tanh(acc[0]), fast_tanh(acc[1]),
                       fast_tanh(acc[2]), fast_tanh(acc[3])};
          *(float4*)&ob[colb] = ov;
        }
      }
    }
    // no trailing barrier: STVX(p+1) writes only this wave's own-sample rows
    // (other waves' S3 reads of those bytes feed masked outputs only);
    // S1(p+1)'s yT writes are fenced from S2(p)'s reads by bar C.
  }
  #undef LOADP
  #undef STV1
  #undef STVX
}

extern "C" void kernel_launch(void* const* d_in, const int* in_sizes, int n_in,
                              void* d_out, int out_size, void* d_ws, size_t ws_size,
                              hipStream_t stream) {
  const float* x     = (const float*)d_in[0];
  const float* embed = (const float*)d_in[2];
  const float* gcn_w = (const float*)d_in[3];
  const float* gcn_b = (const float*)d_in[4];
  const float* w1    = (const float*)d_in[5];
  const float* b1    = (const float*)d_in[6];
  const float* w2    = (const float*)d_in[7];
  const float* b2    = (const float*)d_in[8];
  float* out = (float*)d_out;

  const int batch = in_sizes[0] / (NF * WIN);      // 8192
  const int nPairs = batch / 2;                    // 4096
  const int blocks = 256;
  const int ppb = (nPairs + blocks - 1) / blocks;  // 16 pairs per block
  const int nIt = (ppb + 1) / 2;                   // 2 pair-groups per block

  prune_kernel<<<2, 512, 0, stream>>>(embed, gcn_w, gcn_b, w1, b1, w2, b2, d_ws);
  forward_kernel<<<blocks, 1024, 0, stream>>>(x, d_ws, out, nPairs, nIt, ppb);
}

// Round 7
// 171.316 us; speedup vs baseline: 1.0048x; 1.0048x over previous
//
#include <hip/hip_runtime.h>
#include <hip/hip_bf16.h>
#include <stdint.h>

#define NF 51
#define NF2 (51*51)
#define WIN 100
#define EMB 12
#define FIN 112
#define HID 60
#define NPRUNE 1561
#define SORTN 4096

// ws layout (prepped by prune_kernel; forward stages first WS_STAGE bytes linearly)
#define WS_WX    0        // f16 [112][104] Wx rows   (k<100 real; 100..103 = 0)
#define WS_W1    23296    // f16 [64][104]  w1 rows   (k==100 -> b1; pads 0)
#define WS_W2    36608    // f16 [112][72]  w2 rows   (k==60  -> b2; pads 0)
#define WS_ADJ   52736    // f16 [64][72]   adj rows  (k=51..62 -> E2, k=63 -> 1)
#define WS_YTI   61952    // f16 [112][13]  yT D-fold init (gw_emb | gcn_b/one)
#define WS_STAGE 52736

// forward LDS: per group, sHX [102][104] f16 (x-staging ALIASED with h2) + yT.
#define LDS_GRP0 52736
#define YT_OFF   10608    // f16 units into group region (sHX = 102*104 f16)
#define GRP_SPAN 53472    // bytes: sHX 21216 + yT 32256
#define LDS_TOTAL 159680

typedef _Float16 f16;
typedef _Float16 f16x8 __attribute__((ext_vector_type(8)));
typedef _Float16 f16x4 __attribute__((ext_vector_type(4)));
typedef float f32x4 __attribute__((ext_vector_type(4)));

__device__ __forceinline__ float fast_tanh(float x) {
  float xa = fminf(fmaxf(x, -15.f), 15.f);
  float e = __expf(2.f * xa);
  return (e - 1.f) * __builtin_amdgcn_rcpf(e + 1.f);
}

// T4 barrier: LDS-visibility wait only; vmcnt NOT drained.
#define BAR() do { asm volatile("s_waitcnt lgkmcnt(0)" ::: "memory"); \
  __builtin_amdgcn_s_barrier(); asm volatile("" ::: "memory"); } while (0)

// ---------------- Kernel 1: graph construction + greedy prune + prep ----------------
__global__ __launch_bounds__(512) void prune_kernel(const float* __restrict__ embed,
                                                    const float* __restrict__ gcn_w,
                                                    const float* __restrict__ gcn_b,
                                                    const float* __restrict__ w1,
                                                    const float* __restrict__ b1,
                                                    const float* __restrict__ w2,
                                                    const float* __restrict__ b2,
                                                    void* __restrict__ ws) {
  const int t = threadIdx.x;
  char* wsb = (char*)ws;

  if (blockIdx.x == 1) {
    f16* wxT = (f16*)(wsb + WS_WX);
    for (int u = t; u < 112*104; u += 512) {
      int nn = u / 104, k = u - nn*104;
      wxT[u] = (f16)((nn < WIN && k < WIN) ? gcn_w[nn*FIN + k] : 0.f);
    }
    f16* w1T = (f16*)(wsb + WS_W1);
    for (int u = t; u < 64*104; u += 512) {
      int nn = u / 104, k = u - nn*104;
      float v = 0.f;
      if (nn < HID) { if (k < WIN) v = w1[nn*WIN + k]; else if (k == WIN) v = b1[nn]; }
      w1T[u] = (f16)v;
    }
    f16* w2T = (f16*)(wsb + WS_W2);
    for (int u = t; u < 112*72; u += 512) {
      int nn = u / 72, k = u - nn*72;
      float v = 0.f;
      if (nn < WIN) { if (k < HID) v = w2[nn*HID + k]; else if (k == HID) v = b2[nn]; }
      w2T[u] = (f16)v;
    }
    f16* ytI = (f16*)(wsb + WS_YTI);
    for (int u = t; u < 112*13; u += 512) {
      int win = u / 13, e = u - win*13;
      float v = 0.f;
      if (win < WIN) v = (e < 12) ? gcn_w[win*FIN + WIN + e] : gcn_b[win];
      else if (win == WIN && e == 12) v = 1.f;
      ytI[u] = (f16)v;
    }
    return;
  }

  __shared__ float sA[NF * 52];
  __shared__ unsigned long long sKey[SORTN];
  __shared__ float sNrm[NF];
  __shared__ float sDinv[NF];
  __shared__ float sRow[NF];
  __shared__ float sCol[NF];
  __shared__ float sRowS[NF];
  __shared__ float sColS[NF];
  __shared__ float sEmb[NF * EMB];
  __shared__ float sE2[NF * EMB];
  __shared__ unsigned char sMask[NF2];
  __shared__ unsigned long long sSusp[64];
  __shared__ int sCand[256];
  __shared__ int sCnt[17];
  __shared__ int sNS;
  __shared__ int sNC;
  __shared__ int sTotal;

  for (int u = t; u < NF * EMB; u += 512) sEmb[u] = embed[u];
  for (int u = t; u < NF2; u += 512) sMask[u] = 0;
  if (t == 0) { sNS = 0; sNC = 0; sTotal = 0; }
  __syncthreads();
  if (t < NF) {
    float s = 0.f;
    for (int e = 0; e < EMB; e++) { float w = sEmb[t*EMB + e]; s += w * w; }
    sNrm[t] = sqrtf(s);
  }
  __syncthreads();
  for (int u = t; u < NF2; u += 512) {
    int r = u / NF, c = u % NF;
    float d = 0.f;
    for (int e = 0; e < EMB; e++) d += sEmb[r*EMB + e] * sEmb[c*EMB + e];
    sA[r*52 + c] = d / (sNrm[r] * sNrm[c]);
  }
  __syncthreads();

  if (t < NF) {
    float rs = 0.f, cs = 0.f;
    for (int j = 0; j < NF; j++) { rs += sA[t*52 + j]; cs += sA[j*52 + t]; }
    sRow[t] = rs; sCol[t] = cs;
  }
  __syncthreads();

  // ---- STAGE A (cheap): a rejection of (r,c,v) at visit time requires
  // sum_at_visit <= v on BOTH row and col; sums only increase, so
  // sRow0>v || sCol0>v => unconditionally accepted. Survivors = candidates.
  {
    int myCnt = 0;
    for (int u = t; u < NF2; u += 512) {
      int r = u / NF, c = u % NF;
      float v = sA[r*52 + c];
      if (v < 0.f) {
        myCnt++;
        if (sRow[r] <= v && sCol[c] <= v) {
          int slot = atomicAdd(&sNC, 1);
          if (slot < 256) sCand[slot] = u;
        }
      }
    }
    if (myCnt) atomicAdd(&sTotal, myCnt);
  }
  __syncthreads();
  // ---- STAGE B (sharpened): visit-time sum >= S0 + sum(-v_j) over earlier
  // (ascending (v,idx)) negatives in the row/col — every processed entry
  // contributes >= -v_j (accept: -v_j; reject: mx-v_j > -v_j). Candidates
  // passing this bound are definitely accepted; the rest are suspects.
  if (sNC <= 256) {
    const int nC = sNC;
    for (int i = t; i < nC; i += 512) {
      int u = sCand[i];
      int r = u / NF, c = u - r*NF;
      float v = sA[r*52 + c];
      float Pr = 0.f, Pc = 0.f;
      for (int j = 0; j < NF; j++) {
        float a = sA[r*52 + j];
        if (a < 0.f && (a < v || (a == v && r*NF + j < u))) Pr -= a;
        float b = sA[j*52 + c];
        if (b < 0.f && (b < v || (b == v && j*NF + c < u))) Pc -= b;
      }
      bool okS = ((sRow[r] + Pr - v) > 0.f) || ((sCol[c] + Pc - v) > 0.f);
      if (!okS) {
        int slot = atomicAdd(&sNS, 1);
        if (slot < 64) {
          unsigned int b = __float_as_uint(v);   // negative -> monotone map ~b
          sSusp[slot] = ((unsigned long long)(~b) << 32) | (unsigned int)u;
          sMask[u] = 1;
        }
      }
    }
  }
  __syncthreads();
  const bool fastPath = (sTotal > 0) && (sTotal <= NPRUNE) && (sNC <= 256) && (sNS <= 64);

  if (fastPath) {
    if (t < 64) {
      const int lane = t;
      float mx = -3.0e38f;
      for (int u = lane; u < NF2; u += 64) mx = fmaxf(mx, sA[(u / NF)*52 + (u % NF)]);
      for (int o = 32; o > 0; o >>= 1) mx = fmaxf(mx, __shfl_xor(mx, o, 64));
      if (lane < NF) { sRowS[lane] = 0.f; sColS[lane] = 0.f; }
      const int nS = sNS;
      unsigned long long key = (lane < nS) ? sSusp[lane] : ~0ull;
      // in-wave bitonic sort (64 lanes) ascending (value, idx)
      for (int k = 2; k <= 64; k <<= 1) {
        for (int j = k >> 1; j > 0; j >>= 1) {
          unsigned long long other = __shfl_xor(key, j, 64);
          bool up = ((lane & k) == 0);
          bool takeMin = (((lane & j) == 0) == up);
          unsigned long long mn = key < other ? key : other;
          unsigned long long mxk = key < other ? other : key;
          key = takeMin ? mn : mxk;
        }
      }
      // serial exact walk over suspects: visit sums = S0 + exact non-suspect
      // prefix (all accepted) + tracked suspect contributions.
      for (int kk = 0; kk < nS; kk++) {
        unsigned long long kv = __shfl(key, kk, 64);
        unsigned int mb = (unsigned int)(kv >> 32);
        unsigned int idx = (unsigned int)kv;
        float v = __uint_as_float(~mb);            // suspects are negative
        int r = (int)(idx / NF), c = (int)(idx % NF);
        float pr = 0.f, pc = 0.f;
        if (lane < NF) {
          float a = sA[r*52 + lane];
          if (a < 0.f && !sMask[r*NF + lane] &&
              (a < v || (a == v && (unsigned)(r*NF + lane) < idx))) pr = -a;
          float b = sA[lane*52 + c];
          if (b < 0.f && !sMask[lane*NF + c] &&
              (b < v || (b == v && (unsigned)(lane*NF + c) < idx))) pc = -b;
        }
        for (int o = 32; o > 0; o >>= 1) {
          pr += __shfl_xor(pr, o, 64);
          pc += __shfl_xor(pc, o, 64);
        }
        float sumR = sRow[r] + pr + sRowS[r];
        float sumC = sCol[c] + pc + sColS[c];
        bool ok = ((sumR - v) > 0.f) || ((sumC - v) > 0.f);
        if (lane == 0) {
          if (ok) { sA[r*52 + c] = 0.f; sRowS[r] += -v;     sColS[c] += -v; }
          else    { sA[r*52 + c] = mx;  sRowS[r] += mx - v; sColS[c] += mx - v; }
        }
      }
    }
    __syncthreads();
    // all non-suspect negatives accepted -> zero; rejected suspects hold mx>0.
    for (int u = t; u < NF2; u += 512) {
      int r = u / NF, c = u % NF;
      if (sA[r*52 + c] < 0.f) sA[r*52 + c] = 0.f;
    }
  } else {
    // ---- SLOW PATH (exact; compaction + bitonic sort + ballot walk) ----
    int myCnt = 0;
    for (int u = t; u < NF2; u += 512)
      myCnt += (sA[(u / NF)*52 + (u % NF)] < 0.f) ? 1 : 0;
    int incl = myCnt;
    for (int o = 1; o < 64; o <<= 1) {
      int nb = __shfl_up(incl, o, 64);
      if ((t & 63) >= o) incl += nb;
    }
    if ((t & 63) == 63) sCnt[t >> 6] = incl;
    __syncthreads();
    if (t == 0) {
      int run = 0;
      for (int j = 0; j < 8; j++) { int v = sCnt[j]; sCnt[8 + j] = run; run += v; }
      sCnt[16] = run;
    }
    __syncthreads();
    const int total = sCnt[16];
    const int n = (total <= 2048) ? 2048 : SORTN;
    {
      int cpos = sCnt[8 + (t >> 6)] + (incl - myCnt);
      for (int u = t; u < NF2; u += 512) {
        float v = sA[(u / NF)*52 + (u % NF)];
        if (v < 0.f) {
          unsigned int b = __float_as_uint(v);
          sKey[cpos++] = ((unsigned long long)(~b) << 32) | (unsigned int)u;
        }
      }
      for (int u = total + t; u < n; u += 512) sKey[u] = ~0ull;
    }
    __syncthreads();
    for (int kk = 2; kk <= n; kk <<= 1) {
      for (int jj = kk >> 1; jj > 0; jj >>= 1) {
        for (int u = t; u < n; u += 512) {
          int l = u ^ jj;
          if (l > u) {
            unsigned long long a = sKey[u], b = sKey[l];
            bool up = ((u & kk) == 0);
            if ((a > b) == up) { sKey[u] = b; sKey[l] = a; }
          }
        }
        __syncthreads();
      }
    }

    if (t < 64) {
      const int lane = t;
      float mx = -3.0e38f;
      for (int u = lane; u < NF2; u += 64) mx = fmaxf(mx, sA[(u / NF)*52 + (u % NF)]);
      for (int o = 32; o > 0; o >>= 1) mx = fmaxf(mx, __shfl_xor(mx, o, 64));

      int pruned = 0, pos = 0;
      bool toP2 = false;
      while (pruned < NPRUNE && !toP2) {
        int myi = pos + lane;
        unsigned long long kv = (myi < n) ? sKey[myi] : ~0ull;
        unsigned int mb  = (unsigned int)(kv >> 32);
        unsigned int idx = (unsigned int)kv;
        unsigned int vb  = (mb & 0x80000000u) ? (mb & 0x7FFFFFFFu) : ~mb;
        float v = __uint_as_float(vb);
        bool elig = (v < 0.f) && (idx < (unsigned)NF2);
        int r = 0, c2 = 0; bool okl = false;
        if (elig) {
          r = (int)(idx / NF); c2 = (int)(idx % NF);
          float sr = sRow[r], sc = sCol[c2];
          okl = ((sr - v) > 0.f) || ((sc - v) > 0.f);
        }
        unsigned long long bal = __ballot(okl);
        unsigned long long nb = ~bal;
        int nok = (nb == 0ull) ? 64 : (int)__builtin_ctzll(nb);
        int rem = NPRUNE - pruned;
        int take = nok < rem ? nok : rem;
        if (lane < take) {
          sA[r*52 + c2] = 0.f;
          atomicAdd(&sRow[r], -v);
          atomicAdd(&sCol[c2], -v);
        }
        pruned += take; pos += take;
        if (pruned >= NPRUNE) break;
        if (take == 64) continue;
        unsigned int bvb = (unsigned int)__builtin_amdgcn_readlane((int)vb, take);
        int bidx = __builtin_amdgcn_readlane((int)idx, take);
        float bv = __uint_as_float(bvb);
        if (!(bv < 0.f) || bidx >= NF2) { toP2 = true; break; }
        int br = bidx / NF, bc = bidx % NF;
        float sr = sRow[br], sc = sCol[bc];
        bool ok = ((sr - bv) > 0.f) || ((sc - bv) > 0.f);
        if (ok) {
          if (lane == 0) {
            sA[br*52 + bc] = 0.f;
            sRow[br] = sr - bv; sCol[bc] = sc - bv;
          }
          pruned++; pos++;
        } else {
          if (lane == 0) {
            sA[br*52 + bc] = mx;
            sRow[br] = sr + (mx - bv); sCol[bc] = sc + (mx - bv);
          }
          pos++;
        }
      }
      if (toP2) {
        for (int guard = 0; guard < 40000 && pruned < NPRUNE; guard++) {
          float bv = 3.0e38f; int bidx = NF2;
          for (int u = lane; u < NF2; u += 64) {
            float v = sA[(u / NF)*52 + (u % NF)];
            if (v < bv) { bv = v; bidx = u; }
          }
          for (int o = 32; o > 0; o >>= 1) {
            float ov = __shfl_xor(bv, o, 64);
            int  oi = __shfl_xor(bidx, o, 64);
            if (ov < bv || (ov == bv && oi < bidx)) { bv = ov; bidx = oi; }
          }
          int br = bidx / NF, bc = bidx % NF;
          float sr = sRow[br], sc = sCol[bc];
          bool ok = ((sr - bv) > 0.f) || ((sc - bv) > 0.f);
          if (ok) {
            if (bv == 0.f) break;
            if (lane == 0) { sA[br*52+bc] = 0.f; sRow[br] = sr - bv; sCol[bc] = sc - bv; }
            pruned++;
          } else {
            if (bv == mx) break;
            if (lane == 0) { sA[br*52+bc] = mx; sRow[br] = sr + (mx-bv); sCol[bc] = sc + (mx-bv); }
          }
        }
      }
    }
  }
  __syncthreads();

  if (t < NF) {
    float deg = 0.f;
    for (int j = 0; j < NF; j++) {
      float a = sA[t*52 + j];
      float bin = (a != 0.f) ? 1.f : 0.f;
      if (j == t) bin += 1.f;
      deg += bin;
    }
    sDinv[t] = 1.f / sqrtf(deg);
  }
  __syncthreads();

  float* sN = (float*)sKey;   // sKey dead; reuse as norm_adj [51][52]
  for (int u = t; u < NF * 52; u += 512) {
    int r = u / 52, c = u % 52;
    float v = 0.f;
    if (c < NF) {
      float a = sA[r*52 + c];
      float bin = (a != 0.f) ? 1.f : 0.f;
      if (r == c) bin += 1.f;
      v = sDinv[r] * bin * sDinv[c];
    }
    sN[u] = v;
  }
  __syncthreads();

  // E2 = norm_adj @ embed  [51][12]
  for (int u = t; u < NF * EMB; u += 512) {
    int i = u / EMB, e = u % EMB;
    float s2 = 0.f;
    for (int j = 0; j < NF; j++) s2 += sN[i*52 + j] * sEmb[j*EMB + e];
    sE2[u] = s2;
  }
  __syncthreads();

  // adjT with rank-13 D-fold in k=51..63: cols 51..62 <- E2, col 63 <- 1
  f16* adjT = (f16*)(wsb + WS_ADJ);
  for (int u = t; u < 64*72; u += 512) {
    int r = u / 72, k = u - r*72;
    float v = 0.f;
    if (r < NF) {
      if (k < NF) v = sN[r*52 + k];
      else if (k < 63) v = sE2[r*EMB + (k - 51)];
      else if (k == 63) v = 1.f;
    }
    adjT[u] = (f16)v;
  }
}

// ---------------- Kernel 2: persistent fused MFMA forward ----------------
// 256 blocks x 1024 thr = 16 waves/CU; two 8-wave pair-groups share weights.
// TWO barriers per pair (per-wave x staging is wave-local).
// __launch_bounds__(1024, 1): a 16-wave block permits up to 128 VGPR/lane
// (4 waves/SIMD x 512-reg pool); the previous ",4" bound let the allocator
// settle at 64 and spill the 28-reg px prefetch + 32-reg adjf to scratch
// (FETCH +40MB, WRITE +15MB, +37us). min-waves=1 lifts that cap.
__global__ __launch_bounds__(1024, 1) void forward_kernel(
    const float* __restrict__ x, const void* __restrict__ ws,
    float* __restrict__ out, int nPairs, int nIt, int ppb) {
  __shared__ __align__(16) char smem[LDS_TOTAL];
  f16* wxT = (f16*)(smem + WS_WX);
  f16* w1T = (f16*)(smem + WS_W1);
  f16* w2T = (f16*)(smem + WS_W2);

  const int t = threadIdx.x;
  const int wv = t >> 6, lane = t & 63;
  const int gq = wv >> 3, wq = wv & 7;
  const int c = lane & 15, g = lane >> 4;
  const int s = wq >> 2, mt = wq & 3;
  const int rowA = 51*s + 16*mt + c;
  f16* sHX = (f16*)(smem + LDS_GRP0 + gq*GRP_SPAN);  // [102][104]: x then h2
  f16* yT = sHX + YT_OFF;                            // [2][112][72]

  // one-time: stage weights (52736 B linear), zero activation regions
  {
    const f32x4* w4 = (const f32x4*)ws;
    f32x4* s4 = (f32x4*)smem;
    #pragma unroll
    for (int u = 0; u < 4; u++) { int i = t + u*1024; if (i < 3296) s4[i] = w4[i]; }
    f32x4 z = {0.f,0.f,0.f,0.f};
    f32x4* za = (f32x4*)(smem + LDS_GRP0);
    #pragma unroll
    for (int u = 0; u < 7; u++) { int i = t + u*1024; if (i < 6684) za[i] = z; }
  }
  __syncthreads();
  // D-fold init into yT cols 51..63 (both groups, both samples); persists all
  // pairs (S1 writes only node-cols <= 50).
  {
    const f16* ytI = (const f16*)((const char*)ws + WS_YTI);
    f16* yA = (f16*)(smem + LDS_GRP0) + YT_OFF;
    f16* yB = (f16*)(smem + LDS_GRP0 + GRP_SPAN) + YT_OFF;
    for (int u = t; u < 112*13; u += 1024) {
      int win = u / 13, e = u - win*13;
      f16 v = ytI[u];
      int o = win*72 + 51 + e;
      yA[o] = v; yA[8064 + o] = v; yB[o] = v; yB[8064 + o] = v;
    }
  }
  const f16* adjG = (const f16*)((const char*)ws + WS_ADJ);
  f16x8 adjf[4][2];
  #pragma unroll
  for (int N = 0; N < 4; N++) {
    const f16* bp = &adjG[(16*N + c)*72 + 8*g];
    adjf[N][0] = *(const f16x8*)(bp);
    adjf[N][1] = *(const f16x8*)(bp + 32);
  }
  __syncthreads();

  const int s2a = (wq == 7) ? 1 : 0;
  const int wta = (wq == 7) ? 0 : wq;
  const int wtb = wq + 1;                  // second S2 task (s2=1), wq < 6
  const bool aOk = (16*mt + c) < NF;
  const int pair0 = blockIdx.x * ppb;
  const int rowBase = 51*s + 16*mt;
  // own-sample rows only: mt<3 -> 16 rows (400 float4); mt==3 -> 3 rows (75)
  const int uMax = (mt < 3) ? 400 : 75;

  float4 px0, px1, px2, px3, px4, px5, px6;
  #define LOADP(PI) { \
    const float4* xb = (const float4*)(x + (size_t)(PI)*10200 + (size_t)rowBase*100); \
    px0 = xb[lane]; \
    if (lane + 64  < uMax) px1 = xb[lane+64]; \
    if (lane + 128 < uMax) px2 = xb[lane+128]; \
    if (lane + 192 < uMax) px3 = xb[lane+192]; \
    if (lane + 256 < uMax) px4 = xb[lane+256]; \
    if (lane + 320 < uMax) px5 = xb[lane+320]; \
    if (lane + 384 < uMax) px6 = xb[lane+384]; }
  #define STV1(PX, I) { int u = lane + 64*(I); if (u < uMax) { \
    int row = u / 25, q4 = (u - row*25)*4; \
    f16x4 hv = {(f16)(PX).x,(f16)(PX).y,(f16)(PX).z,(f16)(PX).w}; \
    *(f16x4*)&sHX[(rowBase+row)*104 + q4] = hv; } }
  #define STVX() { STV1(px0,0) STV1(px1,1) STV1(px2,2) STV1(px3,3) \
                   STV1(px4,4) STV1(px5,5) STV1(px6,6) }

  { int pi = pair0 + gq; if (pi < nPairs) LOADP(pi); }

  #pragma unroll 1
  for (int p = 0; p < nIt; p++) {
    const int pairIdx = pair0 + 2*p + gq;
    const bool valid = pairIdx < nPairs;
    const bool nvalid = (p + 1 < nIt) && (pairIdx + 2 < nPairs);
    const f16x8 zero8 = {(f16)0,(f16)0,(f16)0,(f16)0,(f16)0,(f16)0,(f16)0,(f16)0};
    const f32x4 zacc = {0.f,0.f,0.f,0.f};

    // ---- per-wave x staging (own rows; compiler waits vmcnt on px use) ----
    if (valid) STVX();
    // issue next pair's loads (latency spans the whole iteration)
    if (nvalid) LOADP(pairIdx + 2);
    asm volatile("s_waitcnt lgkmcnt(0)" ::: "memory");
    __builtin_amdgcn_sched_barrier(0);

    // ---- S1: y = x @ Wx^T ; A-frags = own sX rows; write yT (cols <= 50) ----
    if (valid) {
      const f16* aB = &sHX[rowA*104];
      const f16x8 a0 = *(const f16x8*)(aB +  0 + 8*g);
      const f16x8 a1 = *(const f16x8*)(aB + 32 + 8*g);
      const f16x8 a2 = *(const f16x8*)(aB + 64 + 8*g);
      f16x8 a3 = zero8;
      if (g == 0) a3 = *(const f16x8*)(aB + 96);   // cols 100..103 stale * 0-weights
      f16* yTs = yT + s*8064;
      const int nodeW = 16*mt + 4*g;
      #pragma unroll
      for (int N = 0; N < 7; N++) {
        const f16* bp = &wxT[(16*N + c)*104 + 8*g];
        f16x8 b3v = zero8;
        if (g == 0) b3v = *(const f16x8*)(bp + 96);
        f32x4 acc = zacc;
        acc = __builtin_amdgcn_mfma_f32_16x16x32_f16(a0, *(const f16x8*)(bp     ), acc, 0, 0, 0);
        acc = __builtin_amdgcn_mfma_f32_16x16x32_f16(a1, *(const f16x8*)(bp + 32), acc, 0, 0, 0);
        acc = __builtin_amdgcn_mfma_f32_16x16x32_f16(a2, *(const f16x8*)(bp + 64), acc, 0, 0, 0);
        acc = __builtin_amdgcn_mfma_f32_16x16x32_f16(a3, b3v, acc, 0, 0, 0);
        const int col = 16*N + c;
        if (mt < 3) {
          f16x4 hv = {(f16)acc[0],(f16)acc[1],(f16)acc[2],(f16)acc[3]};
          *(f16x4*)&yTs[col*72 + nodeW] = hv;
        } else {
          #pragma unroll
          for (int r2 = 0; r2 < 4; r2++)
            if (nodeW + r2 < NF) yTs[col*72 + nodeW + r2] = (f16)acc[r2];
        }
      }
    }
    BAR();   // bar B: yT ready; S2(p-1) reads were done via bar C(p-1)

    // ---- S2: h2 = relu(adj_ext @ y_ext) -> sHX (clobbers sX; D-fold rides) ----
    if (valid) {
      {
        const f16* ap = &yT[s2a*8064 + (16*wta + c)*72 + 8*g];
        const f16x8 a0 = *(const f16x8*)(ap);
        const f16x8 a1 = *(const f16x8*)(ap + 32);
        #pragma unroll
        for (int N = 0; N < 4; N++) {
          f32x4 acc = zacc;
          acc = __builtin_amdgcn_mfma_f32_16x16x32_f16(a0, adjf[N][0], acc, 0, 0, 0);
          acc = __builtin_amdgcn_mfma_f32_16x16x32_f16(a1, adjf[N][1], acc, 0, 0, 0);
          const int nd = 16*N + c;
          const int cb = 16*wta + 4*g;
          if (nd < NF && cb < 104) {
            f16x4 hv = {(f16)fmaxf(acc[0],0.f),(f16)fmaxf(acc[1],0.f),
                        (f16)fmaxf(acc[2],0.f),(f16)fmaxf(acc[3],0.f)};
            *(f16x4*)&sHX[(51*s2a + nd)*104 + cb] = hv;
          }
        }
      }
      if (wq < 6) {
        const f16* ap = &yT[8064 + (16*wtb + c)*72 + 8*g];
        const f16x8 a0 = *(const f16x8*)(ap);
        const f16x8 a1 = *(const f16x8*)(ap + 32);
        #pragma unroll
        for (int N = 0; N < 4; N++) {
          f32x4 acc = zacc;
          acc = __builtin_amdgcn_mfma_f32_16x16x32_f16(a0, adjf[N][0], acc, 0, 0, 0);
          acc = __builtin_amdgcn_mfma_f32_16x16x32_f16(a1, adjf[N][1], acc, 0, 0, 0);
          const int nd = 16*N + c;
          const int cb = 16*wtb + 4*g;
          if (nd < NF && cb < 104) {
            f16x4 hv = {(f16)fmaxf(acc[0],0.f),(f16)fmaxf(acc[1],0.f),
                        (f16)fmaxf(acc[2],0.f),(f16)fmaxf(acc[3],0.f)};
            *(f16x4*)&sHX[(51 + nd)*104 + cb] = hv;
          }
        }
      }
    }
    BAR();   // bar C: h2 ready; yT reads done

    // ---- S3 (h3 in registers) -> lane-exchange -> S4 -> global ----
    if (valid) {
      const f16* bB = &sHX[rowA*104 + 8*g];   // boundary/overread rows: masked
      const f16x8 hb0 = *(const f16x8*)(bB);
      const f16x8 hb1 = *(const f16x8*)(bB + 32);
      const f16x8 hb2 = *(const f16x8*)(bB + 64);
      f16x8 hb3 = zero8;
      if (g == 0) hb3 = *(const f16x8*)(bB + 96);   // col100==1 -> b1 via w1T k=100

      f32x4 ac0, ac1, ac2, ac3;
      #define S3N(NN, ACC) { \
        const f16* ap = &w1T[(16*(NN) + c)*104 + 8*g]; \
        f16x8 a3v = zero8; if (g == 0) a3v = *(const f16x8*)(ap + 96); \
        ACC = zacc; \
        ACC = __builtin_amdgcn_mfma_f32_16x16x32_f16(*(const f16x8*)(ap     ), hb0, ACC, 0, 0, 0); \
        ACC = __builtin_amdgcn_mfma_f32_16x16x32_f16(*(const f16x8*)(ap + 32), hb1, ACC, 0, 0, 0); \
        ACC = __builtin_amdgcn_mfma_f32_16x16x32_f16(*(const f16x8*)(ap + 64), hb2, ACC, 0, 0, 0); \
        ACC = __builtin_amdgcn_mfma_f32_16x16x32_f16(a3v, hb3, ACC, 0, 0, 0); }
      S3N(0, ac0) S3N(1, ac1) S3N(2, ac2) S3N(3, ac3)
      #undef S3N

      union Qu { f16x4 h; int2 i; };
      Qu q0, q1, q2, q3;
      { f16x4 v = {(f16)fast_tanh(ac0[0]),(f16)fast_tanh(ac0[1]),(f16)fast_tanh(ac0[2]),(f16)fast_tanh(ac0[3])}; q0.h = v; }
      { f16x4 v = {(f16)fast_tanh(ac1[0]),(f16)fast_tanh(ac1[1]),(f16)fast_tanh(ac1[2]),(f16)fast_tanh(ac1[3])}; q1.h = v; }
      { f16x4 v = {(f16)fast_tanh(ac2[0]),(f16)fast_tanh(ac2[1]),(f16)fast_tanh(ac2[2]),(f16)fast_tanh(ac2[3])}; q2.h = v; }
      { f16x4 v = {(f16)fast_tanh(ac3[0]),(f16)fast_tanh(ac3[1]),(f16)fast_tanh(ac3[2]),(f16)fast_tanh(ac3[3])}; q3.h = v; }
      // h3 cols 60..63 = {1,0,0,0}: k=60 one feeds b2 via w2T col 60
      if (g == 3) { q3.i.x = 0x00003C00; q3.i.y = 0; }

      const int srcA = c + 16*((2*g) & 3);
      const int srcB = srcA + 16;
      int A0x=__shfl(q0.i.x,srcA,64), A0y=__shfl(q0.i.y,srcA,64);
      int A1x=__shfl(q1.i.x,srcA,64), A1y=__shfl(q1.i.y,srcA,64);
      int A2x=__shfl(q2.i.x,srcA,64), A2y=__shfl(q2.i.y,srcA,64);
      int A3x=__shfl(q3.i.x,srcA,64), A3y=__shfl(q3.i.y,srcA,64);
      int B0x=__shfl(q0.i.x,srcB,64), B0y=__shfl(q0.i.y,srcB,64);
      int B1x=__shfl(q1.i.x,srcB,64), B1y=__shfl(q1.i.y,srcB,64);
      int B2x=__shfl(q2.i.x,srcB,64), B2y=__shfl(q2.i.y,srcB,64);
      int B3x=__shfl(q3.i.x,srcB,64), B3y=__shfl(q3.i.y,srcB,64);
      const bool hiN = (g & 2) != 0;
      union U8 { int i[4]; f16x8 v; } hA, hB;
      hA.i[0] = hiN ? A1x : A0x; hA.i[1] = hiN ? A1y : A0y;
      hA.i[2] = hiN ? B1x : B0x; hA.i[3] = hiN ? B1y : B0y;
      hB.i[0] = hiN ? A3x : A2x; hB.i[1] = hiN ? A3y : A2y;
      hB.i[2] = hiN ? B3x : B2x; hB.i[3] = hiN ? B3y : B2y;

      float* ob = out + (size_t)pairIdx * 10200 + (size_t)rowA * 100;
      #pragma unroll
      for (int N = 0; N < 7; N++) {
        const f16* ap = &w2T[(16*N + c)*72 + 8*g];
        f32x4 acc = zacc;
        acc = __builtin_amdgcn_mfma_f32_16x16x32_f16(*(const f16x8*)(ap     ), hA.v, acc, 0, 0, 0);
        acc = __builtin_amdgcn_mfma_f32_16x16x32_f16(*(const f16x8*)(ap + 32), hB.v, acc, 0, 0, 0);
        const int colb = 16*N + 4*g;
        if (aOk && colb < WIN) {
          float4 ov = {fast_tanh(acc[0]), fast_tanh(acc[1]),
                       fast_tanh(acc[2]), fast_tanh(acc[3])};
          *(float4*)&ob[colb] = ov;
        }
      }
    }
    // no trailing barrier: STVX(p+1) writes only this wave's own-sample rows
    // (other waves' S3 reads of those bytes feed masked outputs only);
    // S1(p+1)'s yT writes are fenced from S2(p)'s reads by bar C.
  }
  #undef LOADP
  #undef STV1
  #undef STVX
}

extern "C" void kernel_launch(void* const* d_in, const int* in_sizes, int n_in,
                              void* d_out, int out_size, void* d_ws, size_t ws_size,
                              hipStream_t stream) {
  const float* x     = (const float*)d_in[0];
  const float* embed = (const float*)d_in[2];
  const float* gcn_w = (const float*)d_in[3];
  const float* gcn_b = (const float*)d_in[4];
  const float* w1    = (const float*)d_in[5];
  const float* b1    = (const float*)d_in[6];
  const float* w2    = (const float*)d_in[7];
  const float* b2    = (const float*)d_in[8];
  float* out = (float*)d_out;

  const int batch = in_sizes[0] / (NF * WIN);      // 8192
  const int nPairs = batch / 2;                    // 4096
  const int blocks = 256;
  const int ppb = (nPairs + blocks - 1) / blocks;  // 16 pairs per block
  const int nIt = (ppb + 1) / 2;                   // 2 pair-groups per block

  prune_kernel<<<2, 512, 0, stream>>>(embed, gcn_w, gcn_b, w1, b1, w2, b2, d_ws);
  forward_kernel<<<blocks, 1024, 0, stream>>>(x, d_ws, out, nPairs, nIt, ppb);
}

// Round 8
// 136.289 us; speedup vs baseline: 1.2630x; 1.2570x over previous
//
#include <hip/hip_runtime.h>
#include <hip/hip_bf16.h>
#include <stdint.h>

#define NF 51
#define NF2 (51*51)
#define WIN 100
#define EMB 12
#define FIN 112
#define HID 60
#define NPRUNE 1561
#define SORTN 4096

// ws layout (prepped by prune_kernel; forward stages first WS_STAGE bytes linearly)
#define WS_WX    0        // f16 [112][104] Wx rows   (k<100 real; 100..103 = 0)
#define WS_W1    23296    // f16 [64][104]  w1 rows   (k==100 -> b1; pads 0)
#define WS_W2    36608    // f16 [112][72]  w2 rows   (k==60  -> b2; pads 0)
#define WS_ADJ   52736    // f16 [64][72]   adj rows  (k=51..62 -> E2, k=63 -> 1)
#define WS_YTI   61952    // f16 [112][13]  yT D-fold init (gw_emb | gcn_b/one)
#define WS_STAGE 52736

// forward LDS: per group, sHX [102][104] f16 (x-staging ALIASED with h2) + yT.
#define LDS_GRP0 52736
#define YT_OFF   10608    // f16 units into group region (sHX = 102*104 f16)
#define GRP_SPAN 53472    // bytes: sHX 21216 + yT 32256
#define LDS_TOTAL 159680

typedef _Float16 f16;
typedef _Float16 f16x8 __attribute__((ext_vector_type(8)));
typedef _Float16 f16x4 __attribute__((ext_vector_type(4)));
typedef float f32x4 __attribute__((ext_vector_type(4)));

__device__ __forceinline__ float fast_tanh(float x) {
  float xa = fminf(fmaxf(x, -15.f), 15.f);
  float e = __expf(2.f * xa);
  return (e - 1.f) * __builtin_amdgcn_rcpf(e + 1.f);
}

// T4 barrier: LDS-visibility wait only; vmcnt NOT drained.
#define BAR() do { asm volatile("s_waitcnt lgkmcnt(0)" ::: "memory"); \
  __builtin_amdgcn_s_barrier(); asm volatile("" ::: "memory"); } while (0)

// ---------------- Kernel 1: graph construction + greedy prune + prep ----------------
__global__ __launch_bounds__(512) void prune_kernel(const float* __restrict__ embed,
                                                    const float* __restrict__ gcn_w,
                                                    const float* __restrict__ gcn_b,
                                                    const float* __restrict__ w1,
                                                    const float* __restrict__ b1,
                                                    const float* __restrict__ w2,
                                                    const float* __restrict__ b2,
                                                    void* __restrict__ ws) {
  const int t = threadIdx.x;
  char* wsb = (char*)ws;

  if (blockIdx.x == 1) {
    f16* wxT = (f16*)(wsb + WS_WX);
    for (int u = t; u < 112*104; u += 512) {
      int nn = u / 104, k = u - nn*104;
      wxT[u] = (f16)((nn < WIN && k < WIN) ? gcn_w[nn*FIN + k] : 0.f);
    }
    f16* w1T = (f16*)(wsb + WS_W1);
    for (int u = t; u < 64*104; u += 512) {
      int nn = u / 104, k = u - nn*104;
      float v = 0.f;
      if (nn < HID) { if (k < WIN) v = w1[nn*WIN + k]; else if (k == WIN) v = b1[nn]; }
      w1T[u] = (f16)v;
    }
    f16* w2T = (f16*)(wsb + WS_W2);
    for (int u = t; u < 112*72; u += 512) {
      int nn = u / 72, k = u - nn*72;
      float v = 0.f;
      if (nn < WIN) { if (k < HID) v = w2[nn*HID + k]; else if (k == HID) v = b2[nn]; }
      w2T[u] = (f16)v;
    }
    f16* ytI = (f16*)(wsb + WS_YTI);
    for (int u = t; u < 112*13; u += 512) {
      int win = u / 13, e = u - win*13;
      float v = 0.f;
      if (win < WIN) v = (e < 12) ? gcn_w[win*FIN + WIN + e] : gcn_b[win];
      else if (win == WIN && e == 12) v = 1.f;
      ytI[u] = (f16)v;
    }
    return;
  }

  __shared__ float sA[NF * 52];
  __shared__ unsigned long long sKey[SORTN];
  __shared__ float sNrm[NF];
  __shared__ float sDinv[NF];
  __shared__ float sRow[NF];
  __shared__ float sCol[NF];
  __shared__ float sRowS[NF];
  __shared__ float sColS[NF];
  __shared__ float sEmb[NF * EMB];
  __shared__ float sE2[NF * EMB];
  __shared__ unsigned char sMask[NF2];
  __shared__ unsigned long long sSusp[64];
  __shared__ int sCand[256];
  __shared__ int sCnt[17];
  __shared__ int sNS;
  __shared__ int sNC;
  __shared__ int sTotal;

  for (int u = t; u < NF * EMB; u += 512) sEmb[u] = embed[u];
  for (int u = t; u < NF2; u += 512) sMask[u] = 0;
  if (t == 0) { sNS = 0; sNC = 0; sTotal = 0; }
  __syncthreads();
  if (t < NF) {
    float s = 0.f;
    for (int e = 0; e < EMB; e++) { float w = sEmb[t*EMB + e]; s += w * w; }
    sNrm[t] = sqrtf(s);
  }
  __syncthreads();
  for (int u = t; u < NF2; u += 512) {
    int r = u / NF, c = u % NF;
    float d = 0.f;
    for (int e = 0; e < EMB; e++) d += sEmb[r*EMB + e] * sEmb[c*EMB + e];
    sA[r*52 + c] = d / (sNrm[r] * sNrm[c]);
  }
  __syncthreads();

  if (t < NF) {
    float rs = 0.f, cs = 0.f;
    for (int j = 0; j < NF; j++) { rs += sA[t*52 + j]; cs += sA[j*52 + t]; }
    sRow[t] = rs; sCol[t] = cs;
  }
  __syncthreads();

  // ---- STAGE A (cheap): a rejection of (r,c,v) at visit time requires
  // sum_at_visit <= v on BOTH row and col; sums only increase, so
  // sRow0>v || sCol0>v => unconditionally accepted. Survivors = candidates.
  {
    int myCnt = 0;
    for (int u = t; u < NF2; u += 512) {
      int r = u / NF, c = u % NF;
      float v = sA[r*52 + c];
      if (v < 0.f) {
        myCnt++;
        if (sRow[r] <= v && sCol[c] <= v) {
          int slot = atomicAdd(&sNC, 1);
          if (slot < 256) sCand[slot] = u;
        }
      }
    }
    if (myCnt) atomicAdd(&sTotal, myCnt);
  }
  __syncthreads();
  // ---- STAGE B (sharpened): visit-time sum >= S0 + sum(-v_j) over earlier
  // (ascending (v,idx)) negatives in the row/col — every processed entry
  // contributes >= -v_j (accept: -v_j; reject: mx-v_j > -v_j). Candidates
  // passing this bound are definitely accepted; the rest are suspects.
  if (sNC <= 256) {
    const int nC = sNC;
    for (int i = t; i < nC; i += 512) {
      int u = sCand[i];
      int r = u / NF, c = u - r*NF;
      float v = sA[r*52 + c];
      float Pr = 0.f, Pc = 0.f;
      for (int j = 0; j < NF; j++) {
        float a = sA[r*52 + j];
        if (a < 0.f && (a < v || (a == v && r*NF + j < u))) Pr -= a;
        float b = sA[j*52 + c];
        if (b < 0.f && (b < v || (b == v && j*NF + c < u))) Pc -= b;
      }
      bool okS = ((sRow[r] + Pr - v) > 0.f) || ((sCol[c] + Pc - v) > 0.f);
      if (!okS) {
        int slot = atomicAdd(&sNS, 1);
        if (slot < 64) {
          unsigned int b = __float_as_uint(v);   // negative -> monotone map ~b
          sSusp[slot] = ((unsigned long long)(~b) << 32) | (unsigned int)u;
          sMask[u] = 1;
        }
      }
    }
  }
  __syncthreads();
  const bool fastPath = (sTotal > 0) && (sTotal <= NPRUNE) && (sNC <= 256) && (sNS <= 64);

  if (fastPath) {
    if (t < 64) {
      const int lane = t;
      float mx = -3.0e38f;
      for (int u = lane; u < NF2; u += 64) mx = fmaxf(mx, sA[(u / NF)*52 + (u % NF)]);
      for (int o = 32; o > 0; o >>= 1) mx = fmaxf(mx, __shfl_xor(mx, o, 64));
      if (lane < NF) { sRowS[lane] = 0.f; sColS[lane] = 0.f; }
      const int nS = sNS;
      unsigned long long key = (lane < nS) ? sSusp[lane] : ~0ull;
      // in-wave bitonic sort (64 lanes) ascending (value, idx)
      for (int k = 2; k <= 64; k <<= 1) {
        for (int j = k >> 1; j > 0; j >>= 1) {
          unsigned long long other = __shfl_xor(key, j, 64);
          bool up = ((lane & k) == 0);
          bool takeMin = (((lane & j) == 0) == up);
          unsigned long long mn = key < other ? key : other;
          unsigned long long mxk = key < other ? other : key;
          key = takeMin ? mn : mxk;
        }
      }
      // serial exact walk over suspects: visit sums = S0 + exact non-suspect
      // prefix (all accepted) + tracked suspect contributions.
      for (int kk = 0; kk < nS; kk++) {
        unsigned long long kv = __shfl(key, kk, 64);
        unsigned int mb = (unsigned int)(kv >> 32);
        unsigned int idx = (unsigned int)kv;
        float v = __uint_as_float(~mb);            // suspects are negative
        int r = (int)(idx / NF), c = (int)(idx % NF);
        float pr = 0.f, pc = 0.f;
        if (lane < NF) {
          float a = sA[r*52 + lane];
          if (a < 0.f && !sMask[r*NF + lane] &&
              (a < v || (a == v && (unsigned)(r*NF + lane) < idx))) pr = -a;
          float b = sA[lane*52 + c];
          if (b < 0.f && !sMask[lane*NF + c] &&
              (b < v || (b == v && (unsigned)(lane*NF + c) < idx))) pc = -b;
        }
        for (int o = 32; o > 0; o >>= 1) {
          pr += __shfl_xor(pr, o, 64);
          pc += __shfl_xor(pc, o, 64);
        }
        float sumR = sRow[r] + pr + sRowS[r];
        float sumC = sCol[c] + pc + sColS[c];
        bool ok = ((sumR - v) > 0.f) || ((sumC - v) > 0.f);
        if (lane == 0) {
          if (ok) { sA[r*52 + c] = 0.f; sRowS[r] += -v;     sColS[c] += -v; }
          else    { sA[r*52 + c] = mx;  sRowS[r] += mx - v; sColS[c] += mx - v; }
        }
      }
    }
    __syncthreads();
    // all non-suspect negatives accepted -> zero; rejected suspects hold mx>0.
    for (int u = t; u < NF2; u += 512) {
      int r = u / NF, c = u % NF;
      if (sA[r*52 + c] < 0.f) sA[r*52 + c] = 0.f;
    }
  } else {
    // ---- SLOW PATH (exact; compaction + bitonic sort + ballot walk) ----
    int myCnt = 0;
    for (int u = t; u < NF2; u += 512)
      myCnt += (sA[(u / NF)*52 + (u % NF)] < 0.f) ? 1 : 0;
    int incl = myCnt;
    for (int o = 1; o < 64; o <<= 1) {
      int nb = __shfl_up(incl, o, 64);
      if ((t & 63) >= o) incl += nb;
    }
    if ((t & 63) == 63) sCnt[t >> 6] = incl;
    __syncthreads();
    if (t == 0) {
      int run = 0;
      for (int j = 0; j < 8; j++) { int v = sCnt[j]; sCnt[8 + j] = run; run += v; }
      sCnt[16] = run;
    }
    __syncthreads();
    const int total = sCnt[16];
    const int n = (total <= 2048) ? 2048 : SORTN;
    {
      int cpos = sCnt[8 + (t >> 6)] + (incl - myCnt);
      for (int u = t; u < NF2; u += 512) {
        float v = sA[(u / NF)*52 + (u % NF)];
        if (v < 0.f) {
          unsigned int b = __float_as_uint(v);
          sKey[cpos++] = ((unsigned long long)(~b) << 32) | (unsigned int)u;
        }
      }
      for (int u = total + t; u < n; u += 512) sKey[u] = ~0ull;
    }
    __syncthreads();
    for (int kk = 2; kk <= n; kk <<= 1) {
      for (int jj = kk >> 1; jj > 0; jj >>= 1) {
        for (int u = t; u < n; u += 512) {
          int l = u ^ jj;
          if (l > u) {
            unsigned long long a = sKey[u], b = sKey[l];
            bool up = ((u & kk) == 0);
            if ((a > b) == up) { sKey[u] = b; sKey[l] = a; }
          }
        }
        __syncthreads();
      }
    }

    if (t < 64) {
      const int lane = t;
      float mx = -3.0e38f;
      for (int u = lane; u < NF2; u += 64) mx = fmaxf(mx, sA[(u / NF)*52 + (u % NF)]);
      for (int o = 32; o > 0; o >>= 1) mx = fmaxf(mx, __shfl_xor(mx, o, 64));

      int pruned = 0, pos = 0;
      bool toP2 = false;
      while (pruned < NPRUNE && !toP2) {
        int myi = pos + lane;
        unsigned long long kv = (myi < n) ? sKey[myi] : ~0ull;
        unsigned int mb  = (unsigned int)(kv >> 32);
        unsigned int idx = (unsigned int)kv;
        unsigned int vb  = (mb & 0x80000000u) ? (mb & 0x7FFFFFFFu) : ~mb;
        float v = __uint_as_float(vb);
        bool elig = (v < 0.f) && (idx < (unsigned)NF2);
        int r = 0, c2 = 0; bool okl = false;
        if (elig) {
          r = (int)(idx / NF); c2 = (int)(idx % NF);
          float sr = sRow[r], sc = sCol[c2];
          okl = ((sr - v) > 0.f) || ((sc - v) > 0.f);
        }
        unsigned long long bal = __ballot(okl);
        unsigned long long nb = ~bal;
        int nok = (nb == 0ull) ? 64 : (int)__builtin_ctzll(nb);
        int rem = NPRUNE - pruned;
        int take = nok < rem ? nok : rem;
        if (lane < take) {
          sA[r*52 + c2] = 0.f;
          atomicAdd(&sRow[r], -v);
          atomicAdd(&sCol[c2], -v);
        }
        pruned += take; pos += take;
        if (pruned >= NPRUNE) break;
        if (take == 64) continue;
        unsigned int bvb = (unsigned int)__builtin_amdgcn_readlane((int)vb, take);
        int bidx = __builtin_amdgcn_readlane((int)idx, take);
        float bv = __uint_as_float(bvb);
        if (!(bv < 0.f) || bidx >= NF2) { toP2 = true; break; }
        int br = bidx / NF, bc = bidx % NF;
        float sr = sRow[br], sc = sCol[bc];
        bool ok = ((sr - bv) > 0.f) || ((sc - bv) > 0.f);
        if (ok) {
          if (lane == 0) {
            sA[br*52 + bc] = 0.f;
            sRow[br] = sr - bv; sCol[bc] = sc - bv;
          }
          pruned++; pos++;
        } else {
          if (lane == 0) {
            sA[br*52 + bc] = mx;
            sRow[br] = sr + (mx - bv); sCol[bc] = sc + (mx - bv);
          }
          pos++;
        }
      }
      if (toP2) {
        for (int guard = 0; guard < 40000 && pruned < NPRUNE; guard++) {
          float bv = 3.0e38f; int bidx = NF2;
          for (int u = lane; u < NF2; u += 64) {
            float v = sA[(u / NF)*52 + (u % NF)];
            if (v < bv) { bv = v; bidx = u; }
          }
          for (int o = 32; o > 0; o >>= 1) {
            float ov = __shfl_xor(bv, o, 64);
            int  oi = __shfl_xor(bidx, o, 64);
            if (ov < bv || (ov == bv && oi < bidx)) { bv = ov; bidx = oi; }
          }
          int br = bidx / NF, bc = bidx % NF;
          float sr = sRow[br], sc = sCol[bc];
          bool ok = ((sr - bv) > 0.f) || ((sc - bv) > 0.f);
          if (ok) {
            if (bv == 0.f) break;
            if (lane == 0) { sA[br*52+bc] = 0.f; sRow[br] = sr - bv; sCol[bc] = sc - bv; }
            pruned++;
          } else {
            if (bv == mx) break;
            if (lane == 0) { sA[br*52+bc] = mx; sRow[br] = sr + (mx-bv); sCol[bc] = sc + (mx-bv); }
          }
        }
      }
    }
  }
  __syncthreads();

  if (t < NF) {
    float deg = 0.f;
    for (int j = 0; j < NF; j++) {
      float a = sA[t*52 + j];
      float bin = (a != 0.f) ? 1.f : 0.f;
      if (j == t) bin += 1.f;
      deg += bin;
    }
    sDinv[t] = 1.f / sqrtf(deg);
  }
  __syncthreads();

  float* sN = (float*)sKey;   // sKey dead; reuse as norm_adj [51][52]
  for (int u = t; u < NF * 52; u += 512) {
    int r = u / 52, c = u % 52;
    float v = 0.f;
    if (c < NF) {
      float a = sA[r*52 + c];
      float bin = (a != 0.f) ? 1.f : 0.f;
      if (r == c) bin += 1.f;
      v = sDinv[r] * bin * sDinv[c];
    }
    sN[u] = v;
  }
  __syncthreads();

  // E2 = norm_adj @ embed  [51][12]
  for (int u = t; u < NF * EMB; u += 512) {
    int i = u / EMB, e = u % EMB;
    float s2 = 0.f;
    for (int j = 0; j < NF; j++) s2 += sN[i*52 + j] * sEmb[j*EMB + e];
    sE2[u] = s2;
  }
  __syncthreads();

  // adjT with rank-13 D-fold in k=51..63: cols 51..62 <- E2, col 63 <- 1
  f16* adjT = (f16*)(wsb + WS_ADJ);
  for (int u = t; u < 64*72; u += 512) {
    int r = u / 72, k = u - r*72;
    float v = 0.f;
    if (r < NF) {
      if (k < NF) v = sN[r*52 + k];
      else if (k < 63) v = sE2[r*EMB + (k - 51)];
      else if (k == 63) v = 1.f;
    }
    adjT[u] = (f16)v;
  }
}

// ---------------- Kernel 2: persistent fused MFMA forward ----------------
// ROUND-5 STRUCTURE (measured 123.5us, no spill): 256 blocks x 1024 thr; two
// 8-wave pair-groups share weights; x staged BLOCK-WIDE coalesced (linear
// float4 -> f16 STV, short px live-range) into sHX which ALIASES h2.
// 4 T4-barriers/pair. K-folds: D/gcn_b ride yT cols 51..63; b1 rides w1T
// k=100; b2 rides w2T k=60. Per-wave staging variants (r6/r7) spill -> slower.
__global__ __launch_bounds__(1024, 4) void forward_kernel(
    const float* __restrict__ x, const void* __restrict__ ws,
    float* __restrict__ out, int nPairs, int nIt, int ppb) {
  __shared__ __align__(16) char smem[LDS_TOTAL];
  f16* wxT = (f16*)(smem + WS_WX);
  f16* w1T = (f16*)(smem + WS_W1);
  f16* w2T = (f16*)(smem + WS_W2);

  const int t = threadIdx.x;
  const int wv = t >> 6, lane = t & 63;
  const int gq = wv >> 3, wq = wv & 7;
  const int tl = t & 511;                 // group-local thread
  const int c = lane & 15, g = lane >> 4;
  const int s = wq >> 2, mt = wq & 3;
  const int rowA = 51*s + 16*mt + c;
  f16* sHX = (f16*)(smem + LDS_GRP0 + gq*GRP_SPAN);  // [102][104]: x then h2
  f16* yT = sHX + YT_OFF;                            // [2][112][72]

  // one-time: stage weights (52736 B linear), zero activation regions
  {
    const f32x4* w4 = (const f32x4*)ws;
    f32x4* s4 = (f32x4*)smem;
    #pragma unroll
    for (int u = 0; u < 4; u++) { int i = t + u*1024; if (i < 3296) s4[i] = w4[i]; }
    f32x4 z = {0.f,0.f,0.f,0.f};
    f32x4* za = (f32x4*)(smem + LDS_GRP0);
    #pragma unroll
    for (int u = 0; u < 7; u++) { int i = t + u*1024; if (i < 6684) za[i] = z; }
  }
  __syncthreads();
  // D-fold init into yT cols 51..63 (both groups, both samples); persists all
  // pairs (S1 writes only node-cols <= 50).
  {
    const f16* ytI = (const f16*)((const char*)ws + WS_YTI);
    f16* yA = (f16*)(smem + LDS_GRP0) + YT_OFF;
    f16* yB = (f16*)(smem + LDS_GRP0 + GRP_SPAN) + YT_OFF;
    for (int u = t; u < 112*13; u += 1024) {
      int win = u / 13, e = u - win*13;
      f16 v = ytI[u];
      int o = win*72 + 51 + e;
      yA[o] = v; yA[8064 + o] = v; yB[o] = v; yB[8064 + o] = v;
    }
  }
  const f16* adjG = (const f16*)((const char*)ws + WS_ADJ);
  f16x8 adjf[4][2];
  #pragma unroll
  for (int N = 0; N < 4; N++) {
    const f16* bp = &adjG[(16*N + c)*72 + 8*g];
    adjf[N][0] = *(const f16x8*)(bp);
    adjf[N][1] = *(const f16x8*)(bp + 32);
  }
  __syncthreads();

  const int s2a = (wq == 7) ? 1 : 0;
  const int wta = (wq == 7) ? 0 : wq;
  const int wtb = wq + 1;                  // second S2 task (s2=1), wq < 6
  const bool aOk = (16*mt + c) < NF;
  const int pair0 = blockIdx.x * ppb;

  float4 p0, p1, p2, p3, p4;
  #define LOADP(PI) { const float4* xb = (const float4*)(x + (size_t)(PI) * 10200); \
    p0 = xb[tl]; p1 = xb[tl+512]; p2 = xb[tl+1024]; p3 = xb[tl+1536]; \
    if (tl < 502) p4 = xb[tl+2048]; }
  #define STVX() { \
    { int row = tl/25, q4 = (tl%25)*4; \
      f16x4 hv = {(f16)p0.x,(f16)p0.y,(f16)p0.z,(f16)p0.w}; *(f16x4*)&sHX[row*104+q4] = hv; } \
    { int V = tl+512; int row = V/25, q4 = (V%25)*4; \
      f16x4 hv = {(f16)p1.x,(f16)p1.y,(f16)p1.z,(f16)p1.w}; *(f16x4*)&sHX[row*104+q4] = hv; } \
    { int V = tl+1024; int row = V/25, q4 = (V%25)*4; \
      f16x4 hv = {(f16)p2.x,(f16)p2.y,(f16)p2.z,(f16)p2.w}; *(f16x4*)&sHX[row*104+q4] = hv; } \
    { int V = tl+1536; int row = V/25, q4 = (V%25)*4; \
      f16x4 hv = {(f16)p3.x,(f16)p3.y,(f16)p3.z,(f16)p3.w}; *(f16x4*)&sHX[row*104+q4] = hv; } \
    if (tl < 502) { int V = tl+2048; int row = V/25, q4 = (V%25)*4; \
      f16x4 hv = {(f16)p4.x,(f16)p4.y,(f16)p4.z,(f16)p4.w}; *(f16x4*)&sHX[row*104+q4] = hv; } }

  // prologue: stage pair0+gq
  { int pi = pair0 + gq; if (pi < nPairs) { LOADP(pi); STVX(); } }

  #pragma unroll 1
  for (int p = 0; p < nIt; p++) {
    const int pairIdx = pair0 + 2*p + gq;
    const bool valid = pairIdx < nPairs;
    const bool nvalid = (p + 1 < nIt) && (pairIdx + 2 < nPairs);
    const f16x8 zero8 = {(f16)0,(f16)0,(f16)0,(f16)0,(f16)0,(f16)0,(f16)0,(f16)0};
    const f32x4 zacc = {0.f,0.f,0.f,0.f};

    BAR();   // bar A: sX(p) visible

    // issue next pair's coalesced loads (consumed at STVX after bar D)
    if (nvalid) LOADP(pairIdx + 2);

    // ---- S1: y = x @ Wx^T ; A-frags from sHX; write yT (node cols <= 50) ----
    if (valid) {
      const f16* aB = &sHX[rowA*104];
      const f16x8 a0 = *(const f16x8*)(aB +  0 + 8*g);
      const f16x8 a1 = *(const f16x8*)(aB + 32 + 8*g);
      const f16x8 a2 = *(const f16x8*)(aB + 64 + 8*g);
      f16x8 a3 = zero8;
      if (g == 0) a3 = *(const f16x8*)(aB + 96);   // cols 100..103 garbage * 0-weights
      f16* yTs = yT + s*8064;
      const int nodeW = 16*mt + 4*g;
      #pragma unroll
      for (int N = 0; N < 7; N++) {
        const f16* bp = &wxT[(16*N + c)*104 + 8*g];
        f16x8 b3v = zero8;
        if (g == 0) b3v = *(const f16x8*)(bp + 96);
        f32x4 acc = zacc;
        acc = __builtin_amdgcn_mfma_f32_16x16x32_f16(a0, *(const f16x8*)(bp     ), acc, 0, 0, 0);
        acc = __builtin_amdgcn_mfma_f32_16x16x32_f16(a1, *(const f16x8*)(bp + 32), acc, 0, 0, 0);
        acc = __builtin_amdgcn_mfma_f32_16x16x32_f16(a2, *(const f16x8*)(bp + 64), acc, 0, 0, 0);
        acc = __builtin_amdgcn_mfma_f32_16x16x32_f16(a3, b3v, acc, 0, 0, 0);
        const int col = 16*N + c;
        if (mt < 3) {
          f16x4 hv = {(f16)acc[0],(f16)acc[1],(f16)acc[2],(f16)acc[3]};
          *(f16x4*)&yTs[col*72 + nodeW] = hv;
        } else {
          #pragma unroll
          for (int r2 = 0; r2 < 4; r2++)
            if (nodeW + r2 < NF) yTs[col*72 + nodeW + r2] = (f16)acc[r2];
        }
      }
    }
    BAR();   // bar B: yT ready; all S1 reads of sX done

    // ---- S2: h2 = relu(adj_ext @ y_ext) -> sHX (clobbers sX; D-fold rides) ----
    if (valid) {
      {
        const f16* ap = &yT[s2a*8064 + (16*wta + c)*72 + 8*g];
        const f16x8 a0 = *(const f16x8*)(ap);
        const f16x8 a1 = *(const f16x8*)(ap + 32);
        #pragma unroll
        for (int N = 0; N < 4; N++) {
          f32x4 acc = zacc;
          acc = __builtin_amdgcn_mfma_f32_16x16x32_f16(a0, adjf[N][0], acc, 0, 0, 0);
          acc = __builtin_amdgcn_mfma_f32_16x16x32_f16(a1, adjf[N][1], acc, 0, 0, 0);
          const int nd = 16*N + c;
          const int cb = 16*wta + 4*g;
          if (nd < NF && cb < 104) {
            f16x4 hv = {(f16)fmaxf(acc[0],0.f),(f16)fmaxf(acc[1],0.f),
                        (f16)fmaxf(acc[2],0.f),(f16)fmaxf(acc[3],0.f)};
            *(f16x4*)&sHX[(51*s2a + nd)*104 + cb] = hv;
          }
        }
      }
      if (wq < 6) {
        const f16* ap = &yT[8064 + (16*wtb + c)*72 + 8*g];
        const f16x8 a0 = *(const f16x8*)(ap);
        const f16x8 a1 = *(const f16x8*)(ap + 32);
        #pragma unroll
        for (int N = 0; N < 4; N++) {
          f32x4 acc = zacc;
          acc = __builtin_amdgcn_mfma_f32_16x16x32_f16(a0, adjf[N][0], acc, 0, 0, 0);
          acc = __builtin_amdgcn_mfma_f32_16x16x32_f16(a1, adjf[N][1], acc, 0, 0, 0);
          const int nd = 16*N + c;
          const int cb = 16*wtb + 4*g;
          if (nd < NF && cb < 104) {
            f16x4 hv = {(f16)fmaxf(acc[0],0.f),(f16)fmaxf(acc[1],0.f),
                        (f16)fmaxf(acc[2],0.f),(f16)fmaxf(acc[3],0.f)};
            *(f16x4*)&sHX[(51 + nd)*104 + cb] = hv;
          }
        }
      }
    }
    BAR();   // bar C: h2 ready; yT reads done

    // ---- S3 (h3 in registers) -> lane-exchange -> S4 -> global ----
    if (valid) {
      const f16* bB = &sHX[rowA*104 + 8*g];   // rows>=102 overread: garbage-OK (masked)
      const f16x8 hb0 = *(const f16x8*)(bB);
      const f16x8 hb1 = *(const f16x8*)(bB + 32);
      const f16x8 hb2 = *(const f16x8*)(bB + 64);
      f16x8 hb3 = zero8;
      if (g == 0) hb3 = *(const f16x8*)(bB + 96);   // col100==1 -> b1 via w1T k=100

      f32x4 ac0, ac1, ac2, ac3;
      #define S3N(NN, ACC) { \
        const f16* ap = &w1T[(16*(NN) + c)*104 + 8*g]; \
        f16x8 a3v = zero8; if (g == 0) a3v = *(const f16x8*)(ap + 96); \
        ACC = zacc; \
        ACC = __builtin_amdgcn_mfma_f32_16x16x32_f16(*(const f16x8*)(ap     ), hb0, ACC, 0, 0, 0); \
        ACC = __builtin_amdgcn_mfma_f32_16x16x32_f16(*(const f16x8*)(ap + 32), hb1, ACC, 0, 0, 0); \
        ACC = __builtin_amdgcn_mfma_f32_16x16x32_f16(*(const f16x8*)(ap + 64), hb2, ACC, 0, 0, 0); \
        ACC = __builtin_amdgcn_mfma_f32_16x16x32_f16(a3v, hb3, ACC, 0, 0, 0); }
      S3N(0, ac0) S3N(1, ac1) S3N(2, ac2) S3N(3, ac3)
      #undef S3N

      union Qu { f16x4 h; int2 i; };
      Qu q0, q1, q2, q3;
      { f16x4 v = {(f16)fast_tanh(ac0[0]),(f16)fast_tanh(ac0[1]),(f16)fast_tanh(ac0[2]),(f16)fast_tanh(ac0[3])}; q0.h = v; }
      { f16x4 v = {(f16)fast_tanh(ac1[0]),(f16)fast_tanh(ac1[1]),(f16)fast_tanh(ac1[2]),(f16)fast_tanh(ac1[3])}; q1.h = v; }
      { f16x4 v = {(f16)fast_tanh(ac2[0]),(f16)fast_tanh(ac2[1]),(f16)fast_tanh(ac2[2]),(f16)fast_tanh(ac2[3])}; q2.h = v; }
      { f16x4 v = {(f16)fast_tanh(ac3[0]),(f16)fast_tanh(ac3[1]),(f16)fast_tanh(ac3[2]),(f16)fast_tanh(ac3[3])}; q3.h = v; }
      // h3 cols 60..63 = {1,0,0,0}: the k=60 one feeds b2 via w2T col 60
      if (g == 3) { q3.i.x = 0x00003C00; q3.i.y = 0; }

      const int srcA = c + 16*((2*g) & 3);
      const int srcB = srcA + 16;
      int A0x=__shfl(q0.i.x,srcA,64), A0y=__shfl(q0.i.y,srcA,64);
      int A1x=__shfl(q1.i.x,srcA,64), A1y=__shfl(q1.i.y,srcA,64);
      int A2x=__shfl(q2.i.x,srcA,64), A2y=__shfl(q2.i.y,srcA,64);
      int A3x=__shfl(q3.i.x,srcA,64), A3y=__shfl(q3.i.y,srcA,64);
      int B0x=__shfl(q0.i.x,srcB,64), B0y=__shfl(q0.i.y,srcB,64);
      int B1x=__shfl(q1.i.x,srcB,64), B1y=__shfl(q1.i.y,srcB,64);
      int B2x=__shfl(q2.i.x,srcB,64), B2y=__shfl(q2.i.y,srcB,64);
      int B3x=__shfl(q3.i.x,srcB,64), B3y=__shfl(q3.i.y,srcB,64);
      const bool hiN = (g & 2) != 0;
      union U8 { int i[4]; f16x8 v; } hA, hB;
      hA.i[0] = hiN ? A1x : A0x; hA.i[1] = hiN ? A1y : A0y;
      hA.i[2] = hiN ? B1x : B0x; hA.i[3] = hiN ? B1y : B0y;
      hB.i[0] = hiN ? A3x : A2x; hB.i[1] = hiN ? A3y : A2y;
      hB.i[2] = hiN ? B3x : B2x; hB.i[3] = hiN ? B3y : B2y;

      float* ob = out + (size_t)pairIdx * 10200 + (size_t)rowA * 100;
      #pragma unroll
      for (int N = 0; N < 7; N++) {
        const f16* ap = &w2T[(16*N + c)*72 + 8*g];
        f32x4 acc = zacc;
        acc = __builtin_amdgcn_mfma_f32_16x16x32_f16(*(const f16x8*)(ap     ), hA.v, acc, 0, 0, 0);
        acc = __builtin_amdgcn_mfma_f32_16x16x32_f16(*(const f16x8*)(ap + 32), hB.v, acc, 0, 0, 0);
        const int colb = 16*N + 4*g;
        if (aOk && colb < WIN) {
          float4 ov = {fast_tanh(acc[0]), fast_tanh(acc[1]),
                       fast_tanh(acc[2]), fast_tanh(acc[3])};
          *(float4*)&ob[colb] = ov;
        }
      }
    }
    BAR();   // bar D: all S3 reads of h2 done -> sHX reusable for next x

    if (nvalid) STVX();
  }
  #undef LOADP
  #undef STVX
}

extern "C" void kernel_launch(void* const* d_in, const int* in_sizes, int n_in,
                              void* d_out, int out_size, void* d_ws, size_t ws_size,
                              hipStream_t stream) {
  const float* x     = (const float*)d_in[0];
  const float* embed = (const float*)d_in[2];
  const float* gcn_w = (const float*)d_in[3];
  const float* gcn_b = (const float*)d_in[4];
  const float* w1    = (const float*)d_in[5];
  const float* b1    = (const float*)d_in[6];
  const float* w2    = (const float*)d_in[7];
  const float* b2    = (const float*)d_in[8];
  float* out = (float*)d_out;

  const int batch = in_sizes[0] / (NF * WIN);      // 8192
  const int nPairs = batch / 2;                    // 4096
  const int blocks = 256;
  const int ppb = (nPairs + blocks - 1) / blocks;  // 16 pairs per block
  const int nIt = (ppb + 1) / 2;                   // 2 pair-groups per block

  prune_kernel<<<2, 512, 0, stream>>>(embed, gcn_w, gcn_b, w1, b1, w2, b2, d_ws);
  forward_kernel<<<blocks, 1024, 0, stream>>>(x, d_ws, out, nPairs, nIt, ppb);
}